// Round 3
// baseline (2139.891 us; speedup 1.0000x reference)
//
#include <hip/hip_runtime.h>
#include <hip/hip_bf16.h>

#define GG 64   // num_graphs (fixed by problem)

// monotone float<->uint key (total order preserved: larger float => larger key)
__device__ __forceinline__ unsigned fenc(float v) {
    unsigned u = __float_as_uint(v);
    return (u & 0x80000000u) ? ~u : (u | 0x80000000u);
}
__device__ __forceinline__ float fdec(unsigned k) {
    unsigned u = (k & 0x80000000u) ? (k ^ 0x80000000u) : ~k;
    return __uint_as_float(u);
}

// ---------------- degree / norm ----------------
__global__ void k_deg(const int* __restrict__ dst, float* __restrict__ deg, int E) {
    int e = blockIdx.x * blockDim.x + threadIdx.x;
    if (e < E) atomicAdd(&deg[dst[e]], 1.0f);
}

__global__ void k_dis(float* deg, int n) {
    int i = blockIdx.x * blockDim.x + threadIdx.x;
    if (i < n) deg[i] = rsqrtf(deg[i] + 1.0f);   // dis = deg^{-1/2}, deg includes self loop
}

// ---------------- hw = h @ W  (W staged in LDS) ----------------
__global__ void k_matmul(const float* __restrict__ h, const float* __restrict__ W,
                         float* __restrict__ hw, int n, int fin, int fout_shift) {
    extern __shared__ float sW[];
    const int fout = 1 << fout_shift;
    for (int i = threadIdx.x; i < fin * fout; i += blockDim.x) sW[i] = W[i];
    __syncthreads();
    long long tid = (long long)blockIdx.x * blockDim.x + threadIdx.x;
    if (tid >= ((long long)n << fout_shift)) return;
    int j = (int)(tid & (fout - 1));
    long long node = tid >> fout_shift;
    const float* row = h + node * fin;
    float acc = 0.f;
    #pragma unroll 4
    for (int k = 0; k < fin; ++k) acc = fmaf(row[k], sW[(k << fout_shift) + j], acc);
    hw[tid] = acc;
}

// ---------------- edge scatter: agg[dst] += hw[src]*dis[src]*dis[dst] ----------------
__global__ void k_edge(const int* __restrict__ src, const int* __restrict__ dst,
                       const float* __restrict__ dis, const float* __restrict__ hw,
                       float* __restrict__ agg, int E, int fout_shift) {
    long long tid = (long long)blockIdx.x * blockDim.x + threadIdx.x;
    if (tid >= ((long long)E << fout_shift)) return;
    int f = (int)(tid & ((1 << fout_shift) - 1));
    long long e = tid >> fout_shift;
    int s = src[e], d = dst[e];
    float w = dis[s] * dis[d];
    atomicAdd(&agg[((long long)d << fout_shift) + f],
              hw[((long long)s << fout_shift) + f] * w);
}

// ---------------- y = agg + selfw*hw + b (in place on agg) + BN stats ----------------
__global__ void k_ystats(const float* __restrict__ hw, const float* __restrict__ bias,
                         const float* __restrict__ dis, float* __restrict__ y,
                         float* __restrict__ stats, int n, int fout_shift) {
    __shared__ float ssum[64], ssq[64];
    const int fout = 1 << fout_shift;
    for (int i = threadIdx.x; i < 64; i += blockDim.x) { ssum[i] = 0.f; ssq[i] = 0.f; }
    __syncthreads();
    long long total = (long long)n << fout_shift;
    long long stride = (long long)gridDim.x * blockDim.x;      // multiple of fout
    long long tid0 = (long long)blockIdx.x * blockDim.x + threadIdx.x;
    int f = (int)(tid0 & (fout - 1));
    float b = bias[f];
    float lsum = 0.f, lsq = 0.f;
    for (long long tid = tid0; tid < total; tid += stride) {
        long long node = tid >> fout_shift;
        float dw = dis[node]; dw *= dw;                        // selfw = dis^2
        float v = y[tid] + dw * hw[tid] + b;
        y[tid] = v;
        lsum += v; lsq += v * v;
    }
    atomicAdd(&ssum[f], lsum);
    atomicAdd(&ssq[f], lsq);
    __syncthreads();
    for (int i = threadIdx.x; i < fout; i += blockDim.x) {
        atomicAdd(&stats[i], ssum[i]);
        atomicAdd(&stats[64 + i], ssq[i]);
    }
}

// ---------------- BN apply + LeakyReLU (in place) ----------------
__global__ void k_bn(float* __restrict__ y, const float* __restrict__ stats,
                     const float* __restrict__ gma, const float* __restrict__ bta,
                     int n, int fout_shift) {
    long long tid = (long long)blockIdx.x * blockDim.x + threadIdx.x;
    if (tid >= ((long long)n << fout_shift)) return;
    int f = (int)(tid & ((1 << fout_shift) - 1));
    float inv_n = 1.0f / (float)n;
    float m = stats[f] * inv_n;
    float var = fmaxf(stats[64 + f] * inv_n - m * m, 0.f);
    float sc = rsqrtf(var + 1e-5f) * gma[f];
    float sh = bta[f] - m * sc;
    float v = y[tid] * sc + sh;
    y[tid] = v > 0.f ? v : 0.1f * v;
}

// ---------------- pooling ----------------
__global__ void k_pinit(float* psum, unsigned* pmaxk, float* pcnt) {
    int i = blockIdx.x * blockDim.x + threadIdx.x;
    if (i < GG * 16) { psum[i] = 0.f; pmaxk[i] = fenc(-3.0e38f); }
    if (i < GG) pcnt[i] = 0.f;
}

__global__ void k_pool(const float* __restrict__ h, const int* __restrict__ batch,
                       float* __restrict__ psum, unsigned* __restrict__ pmaxk,
                       float* __restrict__ pcnt, int n) {
    int tid = blockIdx.x * blockDim.x + threadIdx.x;
    if (tid >= n * 16) return;
    int node = tid >> 4, f = tid & 15;
    int g = batch[node];
    float v = h[tid];
    atomicAdd(&psum[(g << 4) + f], v);
    atomicMax(&pmaxk[(g << 4) + f], fenc(v));
    if (f == 0) atomicAdd(&pcnt[g], 1.0f);
}

// ---------------- head: attention pooling + MLP + sigmoid ----------------
__global__ void k_head(const float* __restrict__ psum, const unsigned* __restrict__ pmaxk,
                       const float* __restrict__ pcnt,
                       const float* __restrict__ attn_w, const float* __restrict__ attn_b,
                       const float* __restrict__ fc1_w, const float* __restrict__ fc1_b,
                       const float* __restrict__ fc2_w, const float* __restrict__ fc2_b,
                       const float* __restrict__ out_w, const float* __restrict__ out_b,
                       float* __restrict__ out) {
    int g = threadIdx.x;
    if (g >= GG) return;
    float xs[16], xm[16], xx[16];
    float c = fmaxf(pcnt[g], 1.0f);
    for (int f = 0; f < 16; ++f) {
        xs[f] = psum[(g << 4) + f];
        xm[f] = xs[f] / c;
        xx[f] = fdec(pmaxk[(g << 4) + f]);
    }
    // pooled = [mean, max, sum] ; logits = pooled @ attn_w + attn_b
    float lg[3];
    for (int cI = 0; cI < 3; ++cI) {
        float a = attn_b[cI];
        for (int f = 0; f < 16; ++f) {
            a += xm[f] * attn_w[f * 3 + cI];
            a += xx[f] * attn_w[(16 + f) * 3 + cI];
            a += xs[f] * attn_w[(32 + f) * 3 + cI];
        }
        lg[cI] = a;
    }
    float mx = fmaxf(lg[0], fmaxf(lg[1], lg[2]));
    float e0 = expf(lg[0] - mx), e1 = expf(lg[1] - mx), e2 = expf(lg[2] - mx);
    float inv = 1.0f / (e0 + e1 + e2);
    float a0 = e0 * inv, a1 = e1 * inv, a2 = e2 * inv;
    float xg[16];
    for (int f = 0; f < 16; ++f) xg[f] = a0 * xm[f] + a1 * xx[f] + a2 * xs[f];
    float t1[16];
    for (int j = 0; j < 16; ++j) {
        float a = fc1_b[j];
        for (int k = 0; k < 16; ++k) a += xg[k] * fc1_w[k * 16 + j];
        t1[j] = a > 0.f ? a : 0.1f * a;
    }
    float t2[8];
    for (int j = 0; j < 8; ++j) {
        float a = fc2_b[j];
        for (int k = 0; k < 16; ++k) a += t1[k] * fc2_w[k * 8 + j];
        t2[j] = a > 0.f ? a : 0.1f * a;
    }
    float o = out_b[0];
    for (int k = 0; k < 8; ++k) o += t2[k] * out_w[k];
    o = 1.0f / (1.0f + expf(-o));
    out[g] = o;   // fp32 output, matching reference dtype
}

extern "C" void kernel_launch(void* const* d_in, const int* in_sizes, int n_in,
                              void* d_out, int out_size, void* d_ws, size_t ws_size,
                              hipStream_t stream) {
    const float* x      = (const float*)d_in[0];
    const float* W1     = (const float*)d_in[1];  const float* b1   = (const float*)d_in[2];
    const float* W2     = (const float*)d_in[3];  const float* b2   = (const float*)d_in[4];
    const float* W3     = (const float*)d_in[5];  const float* b3   = (const float*)d_in[6];
    const float* g1     = (const float*)d_in[7];  const float* be1  = (const float*)d_in[8];
    const float* g2     = (const float*)d_in[9];  const float* be2  = (const float*)d_in[10];
    const float* g3     = (const float*)d_in[11]; const float* be3  = (const float*)d_in[12];
    const float* attn_w = (const float*)d_in[13]; const float* attn_b = (const float*)d_in[14];
    const float* fc1_w  = (const float*)d_in[15]; const float* fc1_b  = (const float*)d_in[16];
    const float* fc2_w  = (const float*)d_in[17]; const float* fc2_b  = (const float*)d_in[18];
    const float* out_w  = (const float*)d_in[19]; const float* out_b  = (const float*)d_in[20];
    const int* edge_index = (const int*)d_in[21];
    const int* batch      = (const int*)d_in[22];

    const int N = in_sizes[0] / 128;
    const int E = in_sizes[21] / 2;
    const int* srcp = edge_index;
    const int* dstp = edge_index + E;

    char* ws = (char*)d_ws;
    float* dis   = (float*)ws;                                   // N floats (pad to 409600 B)
    float* buf1  = (float*)(ws + 409600);                        // N*64 f32  (agg / y / h)
    float* buf2  = buf1 + (size_t)N * 64;                        // N*64 f32  (hw)
    float* stats = buf2 + (size_t)N * 64;                        // 128 floats
    float* psum  = stats + 128;                                  // 64*16
    unsigned* pmaxk = (unsigned*)(psum + GG * 16);               // 64*16
    float* pcnt  = (float*)(pmaxk + GG * 16);                    // 64

    // degree + normalization
    hipMemsetAsync(dis, 0, (size_t)N * 4, stream);
    k_deg<<<(E + 255) / 256, 256, 0, stream>>>(dstp, dis, E);
    k_dis<<<(N + 255) / 256, 256, 0, stream>>>(dis, N);

    // ---- layer 1: x [N,128] -> buf1 [N,64] ----
    k_matmul<<<(unsigned)(((long long)N * 64 + 255) / 256), 256, 128 * 64 * 4, stream>>>(
        x, W1, buf2, N, 128, 6);
    hipMemsetAsync(buf1, 0, (size_t)N * 64 * 4, stream);
    hipMemsetAsync(stats, 0, 512, stream);
    k_edge<<<(unsigned)(((long long)E * 64 + 255) / 256), 256, 0, stream>>>(
        srcp, dstp, dis, buf2, buf1, E, 6);
    k_ystats<<<1024, 256, 0, stream>>>(buf2, b1, dis, buf1, stats, N, 6);
    k_bn<<<(unsigned)(((long long)N * 64 + 255) / 256), 256, 0, stream>>>(
        buf1, stats, g1, be1, N, 6);

    // ---- layer 2: buf1 [N,64] -> buf1 [N,32] ----
    k_matmul<<<(unsigned)(((long long)N * 32 + 255) / 256), 256, 64 * 32 * 4, stream>>>(
        buf1, W2, buf2, N, 64, 5);
    hipMemsetAsync(buf1, 0, (size_t)N * 32 * 4, stream);
    hipMemsetAsync(stats, 0, 512, stream);
    k_edge<<<(unsigned)(((long long)E * 32 + 255) / 256), 256, 0, stream>>>(
        srcp, dstp, dis, buf2, buf1, E, 5);
    k_ystats<<<1024, 256, 0, stream>>>(buf2, b2, dis, buf1, stats, N, 5);
    k_bn<<<(unsigned)(((long long)N * 32 + 255) / 256), 256, 0, stream>>>(
        buf1, stats, g2, be2, N, 5);

    // ---- layer 3: buf1 [N,32] -> buf1 [N,16] ----
    k_matmul<<<(unsigned)(((long long)N * 16 + 255) / 256), 256, 32 * 16 * 4, stream>>>(
        buf1, W3, buf2, N, 32, 4);
    hipMemsetAsync(buf1, 0, (size_t)N * 16 * 4, stream);
    hipMemsetAsync(stats, 0, 512, stream);
    k_edge<<<(unsigned)(((long long)E * 16 + 255) / 256), 256, 0, stream>>>(
        srcp, dstp, dis, buf2, buf1, E, 4);
    k_ystats<<<1024, 256, 0, stream>>>(buf2, b3, dis, buf1, stats, N, 4);
    k_bn<<<(unsigned)(((long long)N * 16 + 255) / 256), 256, 0, stream>>>(
        buf1, stats, g3, be3, N, 4);

    // ---- pooling + head ----
    k_pinit<<<4, 256, 0, stream>>>(psum, pmaxk, pcnt);
    k_pool<<<(unsigned)(((long long)N * 16 + 255) / 256), 256, 0, stream>>>(
        buf1, batch, psum, pmaxk, pcnt, N);
    k_head<<<1, 64, 0, stream>>>(psum, pmaxk, pcnt, attn_w, attn_b,
                                 fc1_w, fc1_b, fc2_w, fc2_b, out_w, out_b,
                                 (float*)d_out);
}

// Round 4
// 1292.239 us; speedup vs baseline: 1.6560x; 1.6560x over previous
//
#include <hip/hip_runtime.h>
#include <hip/hip_bf16.h>

#define GG 64   // num_graphs (fixed by problem)

// ---------------- degree / norm ----------------
__global__ void k_deg(const int* __restrict__ dst, float* __restrict__ deg, int E) {
    int e = blockIdx.x * blockDim.x + threadIdx.x;
    if (e < E) atomicAdd(&deg[dst[e]], 1.0f);
}

__global__ void k_dis(float* deg, int n) {
    int i = blockIdx.x * blockDim.x + threadIdx.x;
    if (i < n) deg[i] = rsqrtf(deg[i] + 1.0f);   // dis = deg^{-1/2}, deg includes self loop
}

// ---------------- hw = h @ W  (W staged in LDS) ----------------
__global__ void k_matmul(const float* __restrict__ h, const float* __restrict__ W,
                         float* __restrict__ hw, int n, int fin, int fout_shift) {
    extern __shared__ float sW[];
    const int fout = 1 << fout_shift;
    for (int i = threadIdx.x; i < fin * fout; i += blockDim.x) sW[i] = W[i];
    __syncthreads();
    long long tid = (long long)blockIdx.x * blockDim.x + threadIdx.x;
    if (tid >= ((long long)n << fout_shift)) return;
    int j = (int)(tid & (fout - 1));
    long long node = tid >> fout_shift;
    const float* row = h + node * fin;
    float acc = 0.f;
    #pragma unroll 4
    for (int k = 0; k < fin; ++k) acc = fmaf(row[k], sW[(k << fout_shift) + j], acc);
    hw[tid] = acc;
}

// ---------------- edge scatter: agg[dst] += hw[src]*dis[src]*dis[dst] ----------------
__global__ void k_edge(const int* __restrict__ src, const int* __restrict__ dst,
                       const float* __restrict__ dis, const float* __restrict__ hw,
                       float* __restrict__ agg, int E, int fout_shift) {
    long long tid = (long long)blockIdx.x * blockDim.x + threadIdx.x;
    if (tid >= ((long long)E << fout_shift)) return;
    int f = (int)(tid & ((1 << fout_shift) - 1));
    long long e = tid >> fout_shift;
    int s = src[e], d = dst[e];
    float w = dis[s] * dis[d];
    atomicAdd(&agg[((long long)d << fout_shift) + f],
              hw[((long long)s << fout_shift) + f] * w);
}

// ---------------- y = agg + selfw*hw + b (in place on agg) + BN stats ----------------
__global__ void k_ystats(const float* __restrict__ hw, const float* __restrict__ bias,
                         const float* __restrict__ dis, float* __restrict__ y,
                         float* __restrict__ stats, int n, int fout_shift) {
    __shared__ float ssum[64], ssq[64];
    const int fout = 1 << fout_shift;
    for (int i = threadIdx.x; i < 64; i += blockDim.x) { ssum[i] = 0.f; ssq[i] = 0.f; }
    __syncthreads();
    long long total = (long long)n << fout_shift;
    long long stride = (long long)gridDim.x * blockDim.x;      // multiple of fout
    long long tid0 = (long long)blockIdx.x * blockDim.x + threadIdx.x;
    int f = (int)(tid0 & (fout - 1));
    float b = bias[f];
    float lsum = 0.f, lsq = 0.f;
    for (long long tid = tid0; tid < total; tid += stride) {
        long long node = tid >> fout_shift;
        float dw = dis[node]; dw *= dw;                        // selfw = dis^2
        float v = y[tid] + dw * hw[tid] + b;
        y[tid] = v;
        lsum += v; lsq += v * v;
    }
    atomicAdd(&ssum[f], lsum);
    atomicAdd(&ssq[f], lsq);
    __syncthreads();
    for (int i = threadIdx.x; i < fout; i += blockDim.x) {
        atomicAdd(&stats[i], ssum[i]);
        atomicAdd(&stats[64 + i], ssq[i]);
    }
}

// ---------------- BN apply + LeakyReLU (in place) ----------------
__global__ void k_bn(float* __restrict__ y, const float* __restrict__ stats,
                     const float* __restrict__ gma, const float* __restrict__ bta,
                     int n, int fout_shift) {
    long long tid = (long long)blockIdx.x * blockDim.x + threadIdx.x;
    if (tid >= ((long long)n << fout_shift)) return;
    int f = (int)(tid & ((1 << fout_shift) - 1));
    float inv_n = 1.0f / (float)n;
    float m = stats[f] * inv_n;
    float var = fmaxf(stats[64 + f] * inv_n - m * m, 0.f);
    float sc = rsqrtf(var + 1e-5f) * gma[f];
    float sh = bta[f] - m * sc;
    float v = y[tid] * sc + sh;
    y[tid] = v > 0.f ? v : 0.1f * v;
}

// ---------------- pooling: one block per graph, zero global atomics ----------------
// batch is sorted, so graph g's nodes are the contiguous range [lo, hi).
__global__ void k_pool_graph(const float* __restrict__ h, const int* __restrict__ batch,
                             int n, float* __restrict__ psum, float* __restrict__ pmax,
                             float* __restrict__ pcnt) {
    const int g = blockIdx.x;
    __shared__ int s_lo, s_hi;
    if (threadIdx.x == 0) {
        int lo = 0, hi = n;
        while (lo < hi) { int mid = (lo + hi) >> 1; if (batch[mid] < g) lo = mid + 1; else hi = mid; }
        s_lo = lo;
        hi = n;
        while (lo < hi) { int mid = (lo + hi) >> 1; if (batch[mid] < g + 1) lo = mid + 1; else hi = mid; }
        s_hi = lo;
    }
    __syncthreads();
    const int start = s_lo, end = s_hi;
    float lsum = 0.f, lmax = -3.0e38f;
    // element idx = node*16 + f; thread t covers f = t&15 only (stride 256 keeps f fixed)
    for (long long idx = (long long)start * 16 + threadIdx.x; idx < (long long)end * 16; idx += blockDim.x) {
        float v = h[idx];
        lsum += v;
        lmax = fmaxf(lmax, v);
    }
    __shared__ float ss[256], sm[256];
    ss[threadIdx.x] = lsum; sm[threadIdx.x] = lmax;
    __syncthreads();
    for (int off = 128; off >= 16; off >>= 1) {
        if (threadIdx.x < off) {
            ss[threadIdx.x] += ss[threadIdx.x + off];
            sm[threadIdx.x] = fmaxf(sm[threadIdx.x], sm[threadIdx.x + off]);
        }
        __syncthreads();
    }
    if (threadIdx.x < 16) {
        psum[g * 16 + threadIdx.x] = ss[threadIdx.x];
        pmax[g * 16 + threadIdx.x] = sm[threadIdx.x];
    }
    if (threadIdx.x == 0) pcnt[g] = (float)(end - start);
}

// ---------------- head: attention pooling + MLP + sigmoid ----------------
__global__ void k_head(const float* __restrict__ psum, const float* __restrict__ pmax,
                       const float* __restrict__ pcnt,
                       const float* __restrict__ attn_w, const float* __restrict__ attn_b,
                       const float* __restrict__ fc1_w, const float* __restrict__ fc1_b,
                       const float* __restrict__ fc2_w, const float* __restrict__ fc2_b,
                       const float* __restrict__ out_w, const float* __restrict__ out_b,
                       float* __restrict__ out) {
    int g = threadIdx.x;
    if (g >= GG) return;
    float xs[16], xm[16], xx[16];
    float c = fmaxf(pcnt[g], 1.0f);
    for (int f = 0; f < 16; ++f) {
        xs[f] = psum[(g << 4) + f];
        xm[f] = xs[f] / c;
        xx[f] = pmax[(g << 4) + f];
    }
    float lg[3];
    for (int cI = 0; cI < 3; ++cI) {
        float a = attn_b[cI];
        for (int f = 0; f < 16; ++f) {
            a += xm[f] * attn_w[f * 3 + cI];
            a += xx[f] * attn_w[(16 + f) * 3 + cI];
            a += xs[f] * attn_w[(32 + f) * 3 + cI];
        }
        lg[cI] = a;
    }
    float mx = fmaxf(lg[0], fmaxf(lg[1], lg[2]));
    float e0 = expf(lg[0] - mx), e1 = expf(lg[1] - mx), e2 = expf(lg[2] - mx);
    float inv = 1.0f / (e0 + e1 + e2);
    float a0 = e0 * inv, a1 = e1 * inv, a2 = e2 * inv;
    float xg[16];
    for (int f = 0; f < 16; ++f) xg[f] = a0 * xm[f] + a1 * xx[f] + a2 * xs[f];
    float t1[16];
    for (int j = 0; j < 16; ++j) {
        float a = fc1_b[j];
        for (int k = 0; k < 16; ++k) a += xg[k] * fc1_w[k * 16 + j];
        t1[j] = a > 0.f ? a : 0.1f * a;
    }
    float t2[8];
    for (int j = 0; j < 8; ++j) {
        float a = fc2_b[j];
        for (int k = 0; k < 16; ++k) a += t1[k] * fc2_w[k * 8 + j];
        t2[j] = a > 0.f ? a : 0.1f * a;
    }
    float o = out_b[0];
    for (int k = 0; k < 8; ++k) o += t2[k] * out_w[k];
    o = 1.0f / (1.0f + expf(-o));
    out[g] = o;
}

extern "C" void kernel_launch(void* const* d_in, const int* in_sizes, int n_in,
                              void* d_out, int out_size, void* d_ws, size_t ws_size,
                              hipStream_t stream) {
    const float* x      = (const float*)d_in[0];
    const float* W1     = (const float*)d_in[1];  const float* b1   = (const float*)d_in[2];
    const float* W2     = (const float*)d_in[3];  const float* b2   = (const float*)d_in[4];
    const float* W3     = (const float*)d_in[5];  const float* b3   = (const float*)d_in[6];
    const float* g1     = (const float*)d_in[7];  const float* be1  = (const float*)d_in[8];
    const float* g2     = (const float*)d_in[9];  const float* be2  = (const float*)d_in[10];
    const float* g3     = (const float*)d_in[11]; const float* be3  = (const float*)d_in[12];
    const float* attn_w = (const float*)d_in[13]; const float* attn_b = (const float*)d_in[14];
    const float* fc1_w  = (const float*)d_in[15]; const float* fc1_b  = (const float*)d_in[16];
    const float* fc2_w  = (const float*)d_in[17]; const float* fc2_b  = (const float*)d_in[18];
    const float* out_w  = (const float*)d_in[19]; const float* out_b  = (const float*)d_in[20];
    const int* edge_index = (const int*)d_in[21];
    const int* batch      = (const int*)d_in[22];

    const int N = in_sizes[0] / 128;
    const int E = in_sizes[21] / 2;
    const int* srcp = edge_index;
    const int* dstp = edge_index + E;

    char* ws = (char*)d_ws;
    float* dis   = (float*)ws;                                   // N floats (pad to 409600 B)
    float* buf1  = (float*)(ws + 409600);                        // N*64 f32  (agg / y / h)
    float* buf2  = buf1 + (size_t)N * 64;                        // N*64 f32  (hw)
    float* stats = buf2 + (size_t)N * 64;                        // 128 floats
    float* psum  = stats + 128;                                  // 64*16
    float* pmax  = psum + GG * 16;                               // 64*16
    float* pcnt  = pmax + GG * 16;                               // 64

    // degree + normalization
    hipMemsetAsync(dis, 0, (size_t)N * 4, stream);
    k_deg<<<(E + 255) / 256, 256, 0, stream>>>(dstp, dis, E);
    k_dis<<<(N + 255) / 256, 256, 0, stream>>>(dis, N);

    // ---- layer 1: x [N,128] -> buf1 [N,64] ----
    k_matmul<<<(unsigned)(((long long)N * 64 + 255) / 256), 256, 128 * 64 * 4, stream>>>(
        x, W1, buf2, N, 128, 6);
    hipMemsetAsync(buf1, 0, (size_t)N * 64 * 4, stream);
    hipMemsetAsync(stats, 0, 512, stream);
    k_edge<<<(unsigned)(((long long)E * 64 + 255) / 256), 256, 0, stream>>>(
        srcp, dstp, dis, buf2, buf1, E, 6);
    k_ystats<<<1024, 256, 0, stream>>>(buf2, b1, dis, buf1, stats, N, 6);
    k_bn<<<(unsigned)(((long long)N * 64 + 255) / 256), 256, 0, stream>>>(
        buf1, stats, g1, be1, N, 6);

    // ---- layer 2: buf1 [N,64] -> buf1 [N,32] ----
    k_matmul<<<(unsigned)(((long long)N * 32 + 255) / 256), 256, 64 * 32 * 4, stream>>>(
        buf1, W2, buf2, N, 64, 5);
    hipMemsetAsync(buf1, 0, (size_t)N * 32 * 4, stream);
    hipMemsetAsync(stats, 0, 512, stream);
    k_edge<<<(unsigned)(((long long)E * 32 + 255) / 256), 256, 0, stream>>>(
        srcp, dstp, dis, buf2, buf1, E, 5);
    k_ystats<<<1024, 256, 0, stream>>>(buf2, b2, dis, buf1, stats, N, 5);
    k_bn<<<(unsigned)(((long long)N * 32 + 255) / 256), 256, 0, stream>>>(
        buf1, stats, g2, be2, N, 5);

    // ---- layer 3: buf1 [N,32] -> buf1 [N,16] ----
    k_matmul<<<(unsigned)(((long long)N * 16 + 255) / 256), 256, 32 * 16 * 4, stream>>>(
        buf1, W3, buf2, N, 32, 4);
    hipMemsetAsync(buf1, 0, (size_t)N * 16 * 4, stream);
    hipMemsetAsync(stats, 0, 512, stream);
    k_edge<<<(unsigned)(((long long)E * 16 + 255) / 256), 256, 0, stream>>>(
        srcp, dstp, dis, buf2, buf1, E, 4);
    k_ystats<<<1024, 256, 0, stream>>>(buf2, b3, dis, buf1, stats, N, 4);
    k_bn<<<(unsigned)(((long long)N * 16 + 255) / 256), 256, 0, stream>>>(
        buf1, stats, g3, be3, N, 4);

    // ---- pooling (block-per-graph, no global atomics) + head ----
    k_pool_graph<<<GG, 256, 0, stream>>>(buf1, batch, N, psum, pmax, pcnt);
    k_head<<<1, 64, 0, stream>>>(psum, pmax, pcnt, attn_w, attn_b,
                                 fc1_w, fc1_b, fc2_w, fc2_b, out_w, out_b,
                                 (float*)d_out);
}

// Round 5
// 1064.174 us; speedup vs baseline: 2.0108x; 1.2143x over previous
//
#include <hip/hip_runtime.h>

#define GG 64   // num_graphs (fixed by problem)
typedef unsigned long long ull;

// ---------------- CSR build: histogram / norm / scan / scatter ----------------
__global__ void k_hist(const int* __restrict__ dst, int* __restrict__ cnt, int E) {
    int e = blockIdx.x * blockDim.x + threadIdx.x;
    if (e < E) atomicAdd(&cnt[dst[e]], 1);
}

__global__ void k_dis(const int* __restrict__ cnt, float* __restrict__ dis, int n) {
    int i = blockIdx.x * blockDim.x + threadIdx.x;
    if (i < n) dis[i] = rsqrtf((float)cnt[i] + 1.0f);   // deg includes self loop
}

// pass A: per-block exclusive scan of cnt -> rp, block totals -> bsum
__global__ void k_scanA(const int* __restrict__ cnt, int* __restrict__ rp,
                        int* __restrict__ bsum, int n) {
    __shared__ int s[256];
    int i = blockIdx.x * 256 + threadIdx.x;
    int v = (i < n) ? cnt[i] : 0;
    s[threadIdx.x] = v;
    __syncthreads();
    for (int off = 1; off < 256; off <<= 1) {
        int t = (threadIdx.x >= off) ? s[threadIdx.x - off] : 0;
        __syncthreads();
        s[threadIdx.x] += t;
        __syncthreads();
    }
    if (i < n) rp[i] = s[threadIdx.x] - v;              // exclusive within block
    if (threadIdx.x == 255) bsum[blockIdx.x] = s[255];
}

// pass B: single block scans block totals (nb <= 512)
__global__ void k_scanB(int* __restrict__ bsum, int nb) {
    __shared__ int s[512];
    int v = (threadIdx.x < nb) ? bsum[threadIdx.x] : 0;
    s[threadIdx.x] = v;
    __syncthreads();
    for (int off = 1; off < 512; off <<= 1) {
        int t = (threadIdx.x >= off) ? s[threadIdx.x - off] : 0;
        __syncthreads();
        s[threadIdx.x] += t;
        __syncthreads();
    }
    if (threadIdx.x < nb) bsum[threadIdx.x] = s[threadIdx.x] - v;   // exclusive
}

// pass C: add block offsets; init cursor; rp[n] = E
__global__ void k_scanC(int* __restrict__ rp, const int* __restrict__ bsum,
                        int* __restrict__ cursor, int n, int E) {
    int i = blockIdx.x * 256 + threadIdx.x;
    if (i < n) {
        int r = rp[i] + bsum[blockIdx.x];
        rp[i] = r;
        cursor[i] = r;
    }
    if (i == 0) rp[n] = E;
}

// scatter edges into dst-sorted order as packed (w, src)
__global__ void k_scatter(const int* __restrict__ src, const int* __restrict__ dst,
                          const float* __restrict__ dis, int* __restrict__ cursor,
                          ull* __restrict__ epack, int E) {
    int e = blockIdx.x * blockDim.x + threadIdx.x;
    if (e >= E) return;
    int s = src[e], d = dst[e];
    float w = dis[s] * dis[d];
    int pos = atomicAdd(&cursor[d], 1);
    epack[pos] = ((ull)__float_as_uint(w) << 32) | (unsigned)s;
}

// ---------------- hw = h @ W  (W staged in LDS) ----------------
__global__ void k_matmul(const float* __restrict__ h, const float* __restrict__ W,
                         float* __restrict__ hw, int n, int fin, int fout_shift) {
    extern __shared__ float sW[];
    const int fout = 1 << fout_shift;
    for (int i = threadIdx.x; i < fin * fout; i += blockDim.x) sW[i] = W[i];
    __syncthreads();
    long long tid = (long long)blockIdx.x * blockDim.x + threadIdx.x;
    if (tid >= ((long long)n << fout_shift)) return;
    int j = (int)(tid & (fout - 1));
    long long node = tid >> fout_shift;
    const float* row = h + node * fin;
    float acc = 0.f;
    #pragma unroll 4
    for (int k = 0; k < fin; ++k) acc = fmaf(row[k], sW[(k << fout_shift) + j], acc);
    hw[tid] = acc;
}

// ---------------- CSR aggregation + self loop + bias + BN stats (no atomics on y) ----
__global__ void k_agg(const float* __restrict__ hw, const ull* __restrict__ epack,
                      const int* __restrict__ rp, const float* __restrict__ dis,
                      const float* __restrict__ bias, float* __restrict__ y,
                      float* __restrict__ stats, int n, int fout_shift) {
    const int fout = 1 << fout_shift;
    __shared__ float ssum[64], ssq[64];
    for (int i = threadIdx.x; i < 64; i += blockDim.x) { ssum[i] = 0.f; ssq[i] = 0.f; }
    __syncthreads();
    const int npb = blockDim.x >> fout_shift;            // nodes per block
    const int local = threadIdx.x >> fout_shift;
    const int f = threadIdx.x & (fout - 1);
    const float b = bias[f];
    float lsum = 0.f, lsq = 0.f;
    for (long long base = (long long)blockIdx.x * npb; base < n;
         base += (long long)gridDim.x * npb) {
        int node = (int)base + local;
        if (node < n) {
            int j0 = rp[node], j1 = rp[node + 1];
            float acc = 0.f;
            for (int j = j0; j < j1; ++j) {
                ull p = epack[j];
                int s = (int)(unsigned)p;
                float w = __uint_as_float((unsigned)(p >> 32));
                acc = fmaf(hw[((long long)s << fout_shift) + f], w, acc);
            }
            float dv = dis[node];
            float v = fmaf(dv * dv, hw[((long long)node << fout_shift) + f], acc) + b;
            y[((long long)node << fout_shift) + f] = v;
            lsum += v; lsq += v * v;
        }
    }
    atomicAdd(&ssum[f], lsum);
    atomicAdd(&ssq[f], lsq);
    __syncthreads();
    for (int i = threadIdx.x; i < fout; i += blockDim.x) {
        atomicAdd(&stats[i], ssum[i]);
        atomicAdd(&stats[64 + i], ssq[i]);
    }
}

// ---------------- BN apply + LeakyReLU (in place) ----------------
__global__ void k_bn(float* __restrict__ y, const float* __restrict__ stats,
                     const float* __restrict__ gma, const float* __restrict__ bta,
                     int n, int fout_shift) {
    long long tid = (long long)blockIdx.x * blockDim.x + threadIdx.x;
    if (tid >= ((long long)n << fout_shift)) return;
    int f = (int)(tid & ((1 << fout_shift) - 1));
    float inv_n = 1.0f / (float)n;
    float m = stats[f] * inv_n;
    float var = fmaxf(stats[64 + f] * inv_n - m * m, 0.f);
    float sc = rsqrtf(var + 1e-5f) * gma[f];
    float sh = bta[f] - m * sc;
    float v = y[tid] * sc + sh;
    y[tid] = v > 0.f ? v : 0.1f * v;
}

// ---------------- pooling: one block per graph (batch sorted) ----------------
__global__ void k_pool_graph(const float* __restrict__ h, const int* __restrict__ batch,
                             int n, float* __restrict__ psum, float* __restrict__ pmax,
                             float* __restrict__ pcnt) {
    const int g = blockIdx.x;
    __shared__ int s_lo, s_hi;
    if (threadIdx.x == 0) {
        int lo = 0, hi = n;
        while (lo < hi) { int mid = (lo + hi) >> 1; if (batch[mid] < g) lo = mid + 1; else hi = mid; }
        s_lo = lo;
        hi = n;
        while (lo < hi) { int mid = (lo + hi) >> 1; if (batch[mid] < g + 1) lo = mid + 1; else hi = mid; }
        s_hi = lo;
    }
    __syncthreads();
    const int start = s_lo, end = s_hi;
    float lsum = 0.f, lmax = -3.0e38f;
    for (long long idx = (long long)start * 16 + threadIdx.x; idx < (long long)end * 16; idx += blockDim.x) {
        float v = h[idx];
        lsum += v;
        lmax = fmaxf(lmax, v);
    }
    __shared__ float ss[256], sm[256];
    ss[threadIdx.x] = lsum; sm[threadIdx.x] = lmax;
    __syncthreads();
    for (int off = 128; off >= 16; off >>= 1) {
        if (threadIdx.x < off) {
            ss[threadIdx.x] += ss[threadIdx.x + off];
            sm[threadIdx.x] = fmaxf(sm[threadIdx.x], sm[threadIdx.x + off]);
        }
        __syncthreads();
    }
    if (threadIdx.x < 16) {
        psum[g * 16 + threadIdx.x] = ss[threadIdx.x];
        pmax[g * 16 + threadIdx.x] = sm[threadIdx.x];
    }
    if (threadIdx.x == 0) pcnt[g] = (float)(end - start);
}

// ---------------- head: attention pooling + MLP + sigmoid ----------------
__global__ void k_head(const float* __restrict__ psum, const float* __restrict__ pmax,
                       const float* __restrict__ pcnt,
                       const float* __restrict__ attn_w, const float* __restrict__ attn_b,
                       const float* __restrict__ fc1_w, const float* __restrict__ fc1_b,
                       const float* __restrict__ fc2_w, const float* __restrict__ fc2_b,
                       const float* __restrict__ out_w, const float* __restrict__ out_b,
                       float* __restrict__ out) {
    int g = threadIdx.x;
    if (g >= GG) return;
    float xs[16], xm[16], xx[16];
    float c = fmaxf(pcnt[g], 1.0f);
    for (int f = 0; f < 16; ++f) {
        xs[f] = psum[(g << 4) + f];
        xm[f] = xs[f] / c;
        xx[f] = pmax[(g << 4) + f];
    }
    float lg[3];
    for (int cI = 0; cI < 3; ++cI) {
        float a = attn_b[cI];
        for (int f = 0; f < 16; ++f) {
            a += xm[f] * attn_w[f * 3 + cI];
            a += xx[f] * attn_w[(16 + f) * 3 + cI];
            a += xs[f] * attn_w[(32 + f) * 3 + cI];
        }
        lg[cI] = a;
    }
    float mx = fmaxf(lg[0], fmaxf(lg[1], lg[2]));
    float e0 = expf(lg[0] - mx), e1 = expf(lg[1] - mx), e2 = expf(lg[2] - mx);
    float inv = 1.0f / (e0 + e1 + e2);
    float a0 = e0 * inv, a1 = e1 * inv, a2 = e2 * inv;
    float xg[16];
    for (int f = 0; f < 16; ++f) xg[f] = a0 * xm[f] + a1 * xx[f] + a2 * xs[f];
    float t1[16];
    for (int j = 0; j < 16; ++j) {
        float a = fc1_b[j];
        for (int k = 0; k < 16; ++k) a += xg[k] * fc1_w[k * 16 + j];
        t1[j] = a > 0.f ? a : 0.1f * a;
    }
    float t2[8];
    for (int j = 0; j < 8; ++j) {
        float a = fc2_b[j];
        for (int k = 0; k < 16; ++k) a += t1[k] * fc2_w[k * 8 + j];
        t2[j] = a > 0.f ? a : 0.1f * a;
    }
    float o = out_b[0];
    for (int k = 0; k < 8; ++k) o += t2[k] * out_w[k];
    o = 1.0f / (1.0f + expf(-o));
    out[g] = o;
}

extern "C" void kernel_launch(void* const* d_in, const int* in_sizes, int n_in,
                              void* d_out, int out_size, void* d_ws, size_t ws_size,
                              hipStream_t stream) {
    const float* x      = (const float*)d_in[0];
    const float* W1     = (const float*)d_in[1];  const float* b1   = (const float*)d_in[2];
    const float* W2     = (const float*)d_in[3];  const float* b2   = (const float*)d_in[4];
    const float* W3     = (const float*)d_in[5];  const float* b3   = (const float*)d_in[6];
    const float* g1     = (const float*)d_in[7];  const float* be1  = (const float*)d_in[8];
    const float* g2     = (const float*)d_in[9];  const float* be2  = (const float*)d_in[10];
    const float* g3     = (const float*)d_in[11]; const float* be3  = (const float*)d_in[12];
    const float* attn_w = (const float*)d_in[13]; const float* attn_b = (const float*)d_in[14];
    const float* fc1_w  = (const float*)d_in[15]; const float* fc1_b  = (const float*)d_in[16];
    const float* fc2_w  = (const float*)d_in[17]; const float* fc2_b  = (const float*)d_in[18];
    const float* out_w  = (const float*)d_in[19]; const float* out_b  = (const float*)d_in[20];
    const int* edge_index = (const int*)d_in[21];
    const int* batch      = (const int*)d_in[22];

    const int N = in_sizes[0] / 128;
    const int E = in_sizes[21] / 2;
    const int* srcp = edge_index;
    const int* dstp = edge_index + E;
    const int nb = (N + 255) / 256;      // scan blocks (<=512 for N<=131072)

    char* ws = (char*)d_ws;
    float* dis    = (float*)(ws);                 // N f32        (512KB slot)
    int*   cnt    = (int*)(ws + 0x80000);         // N int, reused as cursor
    int*   rp     = (int*)(ws + 0x100000);        // N+1 int
    int*   bsum   = (int*)(ws + 0x180000);        // <=512 int
    float* stats  = (float*)(ws + 0x182000);      // 128 f32
    float* psum   = stats + 128;                  // 64*16
    float* pmax   = psum + GG * 16;               // 64*16
    float* pcnt   = pmax + GG * 16;               // 64
    ull*   epack  = (ull*)(ws + 0x190000);        // E * 8B
    float* buf1   = (float*)(ws + 0x190000 + (size_t)E * 8);  // N*64 f32 (y / h)
    float* buf2   = buf1 + (size_t)N * 64;        // N*64 f32 (hw)

    // ---- CSR build (once per call) ----
    hipMemsetAsync(cnt, 0, (size_t)N * 4, stream);
    k_hist<<<(E + 255) / 256, 256, 0, stream>>>(dstp, cnt, E);
    k_dis<<<nb, 256, 0, stream>>>(cnt, dis, N);
    k_scanA<<<nb, 256, 0, stream>>>(cnt, rp, bsum, N);
    k_scanB<<<1, 512, 0, stream>>>(bsum, nb);
    k_scanC<<<nb, 256, 0, stream>>>(rp, bsum, cnt, N, E);    // cnt becomes cursor
    k_scatter<<<(E + 255) / 256, 256, 0, stream>>>(srcp, dstp, dis, cnt, epack, E);

    // ---- layer 1: x [N,128] -> buf1 [N,64] ----
    k_matmul<<<(unsigned)(((long long)N * 64 + 255) / 256), 256, 128 * 64 * 4, stream>>>(
        x, W1, buf2, N, 128, 6);
    hipMemsetAsync(stats, 0, 512, stream);
    k_agg<<<1280, 256, 0, stream>>>(buf2, epack, rp, dis, b1, buf1, stats, N, 6);
    k_bn<<<(unsigned)(((long long)N * 64 + 255) / 256), 256, 0, stream>>>(
        buf1, stats, g1, be1, N, 6);

    // ---- layer 2: buf1 [N,64] -> buf1 [N,32] ----
    k_matmul<<<(unsigned)(((long long)N * 32 + 255) / 256), 256, 64 * 32 * 4, stream>>>(
        buf1, W2, buf2, N, 64, 5);
    hipMemsetAsync(stats, 0, 512, stream);
    k_agg<<<1280, 256, 0, stream>>>(buf2, epack, rp, dis, b2, buf1, stats, N, 5);
    k_bn<<<(unsigned)(((long long)N * 32 + 255) / 256), 256, 0, stream>>>(
        buf1, stats, g2, be2, N, 5);

    // ---- layer 3: buf1 [N,32] -> buf1 [N,16] ----
    k_matmul<<<(unsigned)(((long long)N * 16 + 255) / 256), 256, 32 * 16 * 4, stream>>>(
        buf1, W3, buf2, N, 32, 4);
    hipMemsetAsync(stats, 0, 512, stream);
    k_agg<<<1280, 256, 0, stream>>>(buf2, epack, rp, dis, b3, buf1, stats, N, 4);
    k_bn<<<(unsigned)(((long long)N * 16 + 255) / 256), 256, 0, stream>>>(
        buf1, stats, g3, be3, N, 4);

    // ---- pooling + head ----
    k_pool_graph<<<GG, 256, 0, stream>>>(buf1, batch, N, psum, pmax, pcnt);
    k_head<<<1, 64, 0, stream>>>(psum, pmax, pcnt, attn_w, attn_b,
                                 fc1_w, fc1_b, fc2_w, fc2_b, out_w, out_b,
                                 (float*)d_out);
}

// Round 6
// 827.075 us; speedup vs baseline: 2.5873x; 1.2867x over previous
//
#include <hip/hip_runtime.h>

#define GG 64   // num_graphs (fixed by problem)
typedef unsigned long long ull;

// ---------------- CSR build: histogram / norm / scan / scatter ----------------
__global__ void k_hist(const int* __restrict__ dst, int* __restrict__ cnt, int E) {
    int e = blockIdx.x * blockDim.x + threadIdx.x;
    if (e < E) atomicAdd(&cnt[dst[e]], 1);
}

__global__ void k_dis(const int* __restrict__ cnt, float* __restrict__ dis, int n) {
    int i = blockIdx.x * blockDim.x + threadIdx.x;
    if (i < n) dis[i] = rsqrtf((float)cnt[i] + 1.0f);   // deg includes self loop
}

__global__ void k_scanA(const int* __restrict__ cnt, int* __restrict__ rp,
                        int* __restrict__ bsum, int n) {
    __shared__ int s[256];
    int i = blockIdx.x * 256 + threadIdx.x;
    int v = (i < n) ? cnt[i] : 0;
    s[threadIdx.x] = v;
    __syncthreads();
    for (int off = 1; off < 256; off <<= 1) {
        int t = (threadIdx.x >= off) ? s[threadIdx.x - off] : 0;
        __syncthreads();
        s[threadIdx.x] += t;
        __syncthreads();
    }
    if (i < n) rp[i] = s[threadIdx.x] - v;
    if (threadIdx.x == 255) bsum[blockIdx.x] = s[255];
}

__global__ void k_scanB(int* __restrict__ bsum, int nb) {
    __shared__ int s[512];
    int v = (threadIdx.x < nb) ? bsum[threadIdx.x] : 0;
    s[threadIdx.x] = v;
    __syncthreads();
    for (int off = 1; off < 512; off <<= 1) {
        int t = (threadIdx.x >= off) ? s[threadIdx.x - off] : 0;
        __syncthreads();
        s[threadIdx.x] += t;
        __syncthreads();
    }
    if (threadIdx.x < nb) bsum[threadIdx.x] = s[threadIdx.x] - v;
}

__global__ void k_scanC(int* __restrict__ rp, const int* __restrict__ bsum,
                        int* __restrict__ cursor, int n, int E) {
    int i = blockIdx.x * 256 + threadIdx.x;
    if (i < n) {
        int r = rp[i] + bsum[blockIdx.x];
        rp[i] = r;
        cursor[i] = r;
    }
    if (i == 0) rp[n] = E;
}

__global__ void k_scatter(const int* __restrict__ src, const int* __restrict__ dst,
                          const float* __restrict__ dis, int* __restrict__ cursor,
                          ull* __restrict__ epack, int E) {
    int e = blockIdx.x * blockDim.x + threadIdx.x;
    if (e >= E) return;
    int s = src[e], d = dst[e];
    float w = dis[s] * dis[d];
    int pos = atomicAdd(&cursor[d], 1);
    epack[pos] = ((ull)__float_as_uint(w) << 32) | (unsigned)s;
}

// ---------------- tiled GEMM: hw[n,FOUT] = h[n,FIN] @ W[FIN,FOUT] ----------------
// 256 threads; thread tile 4x4; NT = 4096/FOUT nodes per block; A-tile 32 KB.
template <int FIN, int FOUT>
__global__ __launch_bounds__(256) void k_mm(const float* __restrict__ h,
                                            const float* __restrict__ W,
                                            float* __restrict__ hw, int n) {
    constexpr int FX  = FOUT / 4;        // thread columns
    constexpr int TY  = 256 / FX;        // thread rows
    constexpr int NT  = TY * 4;          // nodes per block
    constexpr int LDA = FIN + ((FOUT == 64) ? 2 : 1);  // bank-spread padding
    __shared__ float sA[NT * LDA];
    __shared__ float sW[FIN * FOUT];

    for (int i = threadIdx.x; i < FIN * FOUT / 4; i += 256)
        ((float4*)sW)[i] = ((const float4*)W)[i];

    const int node0 = blockIdx.x * NT;
    constexpr int LD4 = NT * FIN / 4 / 256;   // float4 loads per thread (8)
    #pragma unroll
    for (int i = 0; i < LD4; ++i) {
        int idx4 = i * 256 + threadIdx.x;
        int row = idx4 / (FIN / 4);
        int c4  = idx4 % (FIN / 4);
        int gn  = node0 + row;
        float4 v = make_float4(0.f, 0.f, 0.f, 0.f);
        if (gn < n) v = ((const float4*)(h + (long long)gn * FIN))[c4];
        float* p = &sA[row * LDA + c4 * 4];
        p[0] = v.x; p[1] = v.y; p[2] = v.z; p[3] = v.w;
    }
    __syncthreads();

    const int tx = threadIdx.x % FX;
    const int ty = threadIdx.x / FX;
    float acc[4][4];
    #pragma unroll
    for (int i = 0; i < 4; ++i)
        #pragma unroll
        for (int j = 0; j < 4; ++j) acc[i][j] = 0.f;

    #pragma unroll 8
    for (int k = 0; k < FIN; ++k) {
        float4 wv = *((const float4*)&sW[k * FOUT + tx * 4]);
        float a0 = sA[(ty * 4 + 0) * LDA + k];
        float a1 = sA[(ty * 4 + 1) * LDA + k];
        float a2 = sA[(ty * 4 + 2) * LDA + k];
        float a3 = sA[(ty * 4 + 3) * LDA + k];
        acc[0][0] = fmaf(a0, wv.x, acc[0][0]); acc[0][1] = fmaf(a0, wv.y, acc[0][1]);
        acc[0][2] = fmaf(a0, wv.z, acc[0][2]); acc[0][3] = fmaf(a0, wv.w, acc[0][3]);
        acc[1][0] = fmaf(a1, wv.x, acc[1][0]); acc[1][1] = fmaf(a1, wv.y, acc[1][1]);
        acc[1][2] = fmaf(a1, wv.z, acc[1][2]); acc[1][3] = fmaf(a1, wv.w, acc[1][3]);
        acc[2][0] = fmaf(a2, wv.x, acc[2][0]); acc[2][1] = fmaf(a2, wv.y, acc[2][1]);
        acc[2][2] = fmaf(a2, wv.z, acc[2][2]); acc[2][3] = fmaf(a2, wv.w, acc[2][3]);
        acc[3][0] = fmaf(a3, wv.x, acc[3][0]); acc[3][1] = fmaf(a3, wv.y, acc[3][1]);
        acc[3][2] = fmaf(a3, wv.z, acc[3][2]); acc[3][3] = fmaf(a3, wv.w, acc[3][3]);
    }

    #pragma unroll
    for (int i = 0; i < 4; ++i) {
        int gn = node0 + ty * 4 + i;
        if (gn < n) {
            float4 o = make_float4(acc[i][0], acc[i][1], acc[i][2], acc[i][3]);
            ((float4*)(hw + (long long)gn * FOUT))[tx] = o;
        }
    }
}

// ---------------- CSR aggregation + self loop + bias + BN stats ----------------
__global__ void k_agg(const float* __restrict__ hw, const ull* __restrict__ epack,
                      const int* __restrict__ rp, const float* __restrict__ dis,
                      const float* __restrict__ bias, float* __restrict__ y,
                      float* __restrict__ stats, int n, int fout_shift) {
    const int fout = 1 << fout_shift;
    __shared__ float ssum[64], ssq[64];
    for (int i = threadIdx.x; i < 64; i += blockDim.x) { ssum[i] = 0.f; ssq[i] = 0.f; }
    __syncthreads();
    const int npb = blockDim.x >> fout_shift;
    const int local = threadIdx.x >> fout_shift;
    const int f = threadIdx.x & (fout - 1);
    const float b = bias[f];
    float lsum = 0.f, lsq = 0.f;
    for (long long base = (long long)blockIdx.x * npb; base < n;
         base += (long long)gridDim.x * npb) {
        int node = (int)base + local;
        if (node < n) {
            int j0 = rp[node], j1 = rp[node + 1];
            float acc = 0.f;
            for (int j = j0; j < j1; ++j) {
                ull p = epack[j];
                int s = (int)(unsigned)p;
                float w = __uint_as_float((unsigned)(p >> 32));
                acc = fmaf(hw[((long long)s << fout_shift) + f], w, acc);
            }
            float dv = dis[node];
            float v = fmaf(dv * dv, hw[((long long)node << fout_shift) + f], acc) + b;
            y[((long long)node << fout_shift) + f] = v;
            lsum += v; lsq += v * v;
        }
    }
    atomicAdd(&ssum[f], lsum);
    atomicAdd(&ssq[f], lsq);
    __syncthreads();
    for (int i = threadIdx.x; i < fout; i += blockDim.x) {
        atomicAdd(&stats[i], ssum[i]);
        atomicAdd(&stats[64 + i], ssq[i]);
    }
}

// ---------------- BN apply + LeakyReLU (in place) ----------------
__global__ void k_bn(float* __restrict__ y, const float* __restrict__ stats,
                     const float* __restrict__ gma, const float* __restrict__ bta,
                     int n, int fout_shift) {
    long long tid = (long long)blockIdx.x * blockDim.x + threadIdx.x;
    if (tid >= ((long long)n << fout_shift)) return;
    int f = (int)(tid & ((1 << fout_shift) - 1));
    float inv_n = 1.0f / (float)n;
    float m = stats[f] * inv_n;
    float var = fmaxf(stats[64 + f] * inv_n - m * m, 0.f);
    float sc = rsqrtf(var + 1e-5f) * gma[f];
    float sh = bta[f] - m * sc;
    float v = y[tid] * sc + sh;
    y[tid] = v > 0.f ? v : 0.1f * v;
}

// ---------------- pooling: one block per graph (batch sorted) ----------------
__global__ void k_pool_graph(const float* __restrict__ h, const int* __restrict__ batch,
                             int n, float* __restrict__ psum, float* __restrict__ pmax,
                             float* __restrict__ pcnt) {
    const int g = blockIdx.x;
    __shared__ int s_lo, s_hi;
    if (threadIdx.x == 0) {
        int lo = 0, hi = n;
        while (lo < hi) { int mid = (lo + hi) >> 1; if (batch[mid] < g) lo = mid + 1; else hi = mid; }
        s_lo = lo;
        hi = n;
        while (lo < hi) { int mid = (lo + hi) >> 1; if (batch[mid] < g + 1) lo = mid + 1; else hi = mid; }
        s_hi = lo;
    }
    __syncthreads();
    const int start = s_lo, end = s_hi;
    float lsum = 0.f, lmax = -3.0e38f;
    for (long long idx = (long long)start * 16 + threadIdx.x; idx < (long long)end * 16; idx += blockDim.x) {
        float v = h[idx];
        lsum += v;
        lmax = fmaxf(lmax, v);
    }
    __shared__ float ss[256], sm[256];
    ss[threadIdx.x] = lsum; sm[threadIdx.x] = lmax;
    __syncthreads();
    for (int off = 128; off >= 16; off >>= 1) {
        if (threadIdx.x < off) {
            ss[threadIdx.x] += ss[threadIdx.x + off];
            sm[threadIdx.x] = fmaxf(sm[threadIdx.x], sm[threadIdx.x + off]);
        }
        __syncthreads();
    }
    if (threadIdx.x < 16) {
        psum[g * 16 + threadIdx.x] = ss[threadIdx.x];
        pmax[g * 16 + threadIdx.x] = sm[threadIdx.x];
    }
    if (threadIdx.x == 0) pcnt[g] = (float)(end - start);
}

// ---------------- head: attention pooling + MLP + sigmoid ----------------
__global__ void k_head(const float* __restrict__ psum, const float* __restrict__ pmax,
                       const float* __restrict__ pcnt,
                       const float* __restrict__ attn_w, const float* __restrict__ attn_b,
                       const float* __restrict__ fc1_w, const float* __restrict__ fc1_b,
                       const float* __restrict__ fc2_w, const float* __restrict__ fc2_b,
                       const float* __restrict__ out_w, const float* __restrict__ out_b,
                       float* __restrict__ out) {
    int g = threadIdx.x;
    if (g >= GG) return;
    float xs[16], xm[16], xx[16];
    float c = fmaxf(pcnt[g], 1.0f);
    for (int f = 0; f < 16; ++f) {
        xs[f] = psum[(g << 4) + f];
        xm[f] = xs[f] / c;
        xx[f] = pmax[(g << 4) + f];
    }
    float lg[3];
    for (int cI = 0; cI < 3; ++cI) {
        float a = attn_b[cI];
        for (int f = 0; f < 16; ++f) {
            a += xm[f] * attn_w[f * 3 + cI];
            a += xx[f] * attn_w[(16 + f) * 3 + cI];
            a += xs[f] * attn_w[(32 + f) * 3 + cI];
        }
        lg[cI] = a;
    }
    float mx = fmaxf(lg[0], fmaxf(lg[1], lg[2]));
    float e0 = expf(lg[0] - mx), e1 = expf(lg[1] - mx), e2 = expf(lg[2] - mx);
    float inv = 1.0f / (e0 + e1 + e2);
    float a0 = e0 * inv, a1 = e1 * inv, a2 = e2 * inv;
    float xg[16];
    for (int f = 0; f < 16; ++f) xg[f] = a0 * xm[f] + a1 * xx[f] + a2 * xs[f];
    float t1[16];
    for (int j = 0; j < 16; ++j) {
        float a = fc1_b[j];
        for (int k = 0; k < 16; ++k) a += xg[k] * fc1_w[k * 16 + j];
        t1[j] = a > 0.f ? a : 0.1f * a;
    }
    float t2[8];
    for (int j = 0; j < 8; ++j) {
        float a = fc2_b[j];
        for (int k = 0; k < 16; ++k) a += t1[k] * fc2_w[k * 8 + j];
        t2[j] = a > 0.f ? a : 0.1f * a;
    }
    float o = out_b[0];
    for (int k = 0; k < 8; ++k) o += t2[k] * out_w[k];
    o = 1.0f / (1.0f + expf(-o));
    out[g] = o;
}

extern "C" void kernel_launch(void* const* d_in, const int* in_sizes, int n_in,
                              void* d_out, int out_size, void* d_ws, size_t ws_size,
                              hipStream_t stream) {
    const float* x      = (const float*)d_in[0];
    const float* W1     = (const float*)d_in[1];  const float* b1   = (const float*)d_in[2];
    const float* W2     = (const float*)d_in[3];  const float* b2   = (const float*)d_in[4];
    const float* W3     = (const float*)d_in[5];  const float* b3   = (const float*)d_in[6];
    const float* g1     = (const float*)d_in[7];  const float* be1  = (const float*)d_in[8];
    const float* g2     = (const float*)d_in[9];  const float* be2  = (const float*)d_in[10];
    const float* g3     = (const float*)d_in[11]; const float* be3  = (const float*)d_in[12];
    const float* attn_w = (const float*)d_in[13]; const float* attn_b = (const float*)d_in[14];
    const float* fc1_w  = (const float*)d_in[15]; const float* fc1_b  = (const float*)d_in[16];
    const float* fc2_w  = (const float*)d_in[17]; const float* fc2_b  = (const float*)d_in[18];
    const float* out_w  = (const float*)d_in[19]; const float* out_b  = (const float*)d_in[20];
    const int* edge_index = (const int*)d_in[21];
    const int* batch      = (const int*)d_in[22];

    const int N = in_sizes[0] / 128;
    const int E = in_sizes[21] / 2;
    const int* srcp = edge_index;
    const int* dstp = edge_index + E;
    const int nb = (N + 255) / 256;

    char* ws = (char*)d_ws;
    float* dis    = (float*)(ws);                 // N f32
    int*   cnt    = (int*)(ws + 0x80000);         // N int, reused as cursor
    int*   rp     = (int*)(ws + 0x100000);        // N+1 int
    int*   bsum   = (int*)(ws + 0x180000);        // <=512 int
    float* stats  = (float*)(ws + 0x182000);      // 128 f32
    float* psum   = stats + 128;
    float* pmax   = psum + GG * 16;
    float* pcnt   = pmax + GG * 16;
    ull*   epack  = (ull*)(ws + 0x190000);        // E * 8B
    float* buf1   = (float*)(ws + 0x190000 + (size_t)E * 8);  // N*64 f32 (y / h)
    float* buf2   = buf1 + (size_t)N * 64;        // N*64 f32 (hw)

    // ---- CSR build ----
    hipMemsetAsync(cnt, 0, (size_t)N * 4, stream);
    k_hist<<<(E + 255) / 256, 256, 0, stream>>>(dstp, cnt, E);
    k_dis<<<nb, 256, 0, stream>>>(cnt, dis, N);
    k_scanA<<<nb, 256, 0, stream>>>(cnt, rp, bsum, N);
    k_scanB<<<1, 512, 0, stream>>>(bsum, nb);
    k_scanC<<<nb, 256, 0, stream>>>(rp, bsum, cnt, N, E);
    k_scatter<<<(E + 255) / 256, 256, 0, stream>>>(srcp, dstp, dis, cnt, epack, E);

    // ---- layer 1 ----
    k_mm<128, 64><<<(N + 63) / 64, 256, 0, stream>>>(x, W1, buf2, N);
    hipMemsetAsync(stats, 0, 512, stream);
    k_agg<<<1280, 256, 0, stream>>>(buf2, epack, rp, dis, b1, buf1, stats, N, 6);
    k_bn<<<(unsigned)(((long long)N * 64 + 255) / 256), 256, 0, stream>>>(
        buf1, stats, g1, be1, N, 6);

    // ---- layer 2 ----
    k_mm<64, 32><<<(N + 127) / 128, 256, 0, stream>>>(buf1, W2, buf2, N);
    hipMemsetAsync(stats, 0, 512, stream);
    k_agg<<<1280, 256, 0, stream>>>(buf2, epack, rp, dis, b2, buf1, stats, N, 5);
    k_bn<<<(unsigned)(((long long)N * 32 + 255) / 256), 256, 0, stream>>>(
        buf1, stats, g2, be2, N, 5);

    // ---- layer 3 ----
    k_mm<32, 16><<<(N + 255) / 256, 256, 0, stream>>>(buf1, W3, buf2, N);
    hipMemsetAsync(stats, 0, 512, stream);
    k_agg<<<1280, 256, 0, stream>>>(buf2, epack, rp, dis, b3, buf1, stats, N, 4);
    k_bn<<<(unsigned)(((long long)N * 16 + 255) / 256), 256, 0, stream>>>(
        buf1, stats, g3, be3, N, 4);

    // ---- pooling + head ----
    k_pool_graph<<<GG, 256, 0, stream>>>(buf1, batch, N, psum, pmax, pcnt);
    k_head<<<1, 64, 0, stream>>>(psum, pmax, pcnt, attn_w, attn_b,
                                 fc1_w, fc1_b, fc2_w, fc2_b, out_w, out_b,
                                 (float*)d_out);
}

// Round 7
// 641.770 us; speedup vs baseline: 3.3344x; 1.2887x over previous
//
#include <hip/hip_runtime.h>

#define GG 64   // num_graphs (fixed by problem)
typedef unsigned long long ull;

// ---------------- CSR build: histogram / norm / scan / scatter ----------------
__global__ void k_hist(const int* __restrict__ dst, int* __restrict__ cnt, int E) {
    int e = blockIdx.x * blockDim.x + threadIdx.x;
    if (e < E) atomicAdd(&cnt[dst[e]], 1);
}

__global__ void k_dis(const int* __restrict__ cnt, float* __restrict__ dis, int n) {
    int i = blockIdx.x * blockDim.x + threadIdx.x;
    if (i < n) dis[i] = rsqrtf((float)cnt[i] + 1.0f);   // deg includes self loop
}

__global__ void k_scanA(const int* __restrict__ cnt, int* __restrict__ rp,
                        int* __restrict__ bsum, int n) {
    __shared__ int s[256];
    int i = blockIdx.x * 256 + threadIdx.x;
    int v = (i < n) ? cnt[i] : 0;
    s[threadIdx.x] = v;
    __syncthreads();
    for (int off = 1; off < 256; off <<= 1) {
        int t = (threadIdx.x >= off) ? s[threadIdx.x - off] : 0;
        __syncthreads();
        s[threadIdx.x] += t;
        __syncthreads();
    }
    if (i < n) rp[i] = s[threadIdx.x] - v;
    if (threadIdx.x == 255) bsum[blockIdx.x] = s[255];
}

__global__ void k_scanB(int* __restrict__ bsum, int nb) {
    __shared__ int s[512];
    int v = (threadIdx.x < nb) ? bsum[threadIdx.x] : 0;
    s[threadIdx.x] = v;
    __syncthreads();
    for (int off = 1; off < 512; off <<= 1) {
        int t = (threadIdx.x >= off) ? s[threadIdx.x - off] : 0;
        __syncthreads();
        s[threadIdx.x] += t;
        __syncthreads();
    }
    if (threadIdx.x < nb) bsum[threadIdx.x] = s[threadIdx.x] - v;
}

__global__ void k_scanC(int* __restrict__ rp, const int* __restrict__ bsum,
                        int* __restrict__ cursor, int n, int E) {
    int i = blockIdx.x * 256 + threadIdx.x;
    if (i < n) {
        int r = rp[i] + bsum[blockIdx.x];
        rp[i] = r;
        cursor[i] = r;
    }
    if (i == 0) rp[n] = E;
}

__global__ void k_scatter(const int* __restrict__ src, const int* __restrict__ dst,
                          const float* __restrict__ dis, int* __restrict__ cursor,
                          ull* __restrict__ epack, int E) {
    int e = blockIdx.x * blockDim.x + threadIdx.x;
    if (e >= E) return;
    int s = src[e], d = dst[e];
    float w = dis[s] * dis[d];
    int pos = atomicAdd(&cursor[d], 1);
    epack[pos] = ((ull)__float_as_uint(w) << 32) | (unsigned)s;
}

// ---------------- tiled GEMM: hw[n,FOUT] = h[n,FIN] @ W[FIN,FOUT] ----------------
template <int FIN, int FOUT>
__global__ __launch_bounds__(256) void k_mm(const float* __restrict__ h,
                                            const float* __restrict__ W,
                                            float* __restrict__ hw, int n) {
    constexpr int FX  = FOUT / 4;
    constexpr int TY  = 256 / FX;
    constexpr int NT  = TY * 4;
    constexpr int LDA = FIN + ((FOUT == 64) ? 2 : 1);
    __shared__ float sA[NT * LDA];
    __shared__ float sW[FIN * FOUT];

    for (int i = threadIdx.x; i < FIN * FOUT / 4; i += 256)
        ((float4*)sW)[i] = ((const float4*)W)[i];

    const int node0 = blockIdx.x * NT;
    constexpr int LD4 = NT * FIN / 4 / 256;
    #pragma unroll
    for (int i = 0; i < LD4; ++i) {
        int idx4 = i * 256 + threadIdx.x;
        int row = idx4 / (FIN / 4);
        int c4  = idx4 % (FIN / 4);
        int gn  = node0 + row;
        float4 v = make_float4(0.f, 0.f, 0.f, 0.f);
        if (gn < n) v = ((const float4*)(h + (long long)gn * FIN))[c4];
        float* p = &sA[row * LDA + c4 * 4];
        p[0] = v.x; p[1] = v.y; p[2] = v.z; p[3] = v.w;
    }
    __syncthreads();

    const int tx = threadIdx.x % FX;
    const int ty = threadIdx.x / FX;
    float acc[4][4];
    #pragma unroll
    for (int i = 0; i < 4; ++i)
        #pragma unroll
        for (int j = 0; j < 4; ++j) acc[i][j] = 0.f;

    #pragma unroll 8
    for (int k = 0; k < FIN; ++k) {
        float4 wv = *((const float4*)&sW[k * FOUT + tx * 4]);
        float a0 = sA[(ty * 4 + 0) * LDA + k];
        float a1 = sA[(ty * 4 + 1) * LDA + k];
        float a2 = sA[(ty * 4 + 2) * LDA + k];
        float a3 = sA[(ty * 4 + 3) * LDA + k];
        acc[0][0] = fmaf(a0, wv.x, acc[0][0]); acc[0][1] = fmaf(a0, wv.y, acc[0][1]);
        acc[0][2] = fmaf(a0, wv.z, acc[0][2]); acc[0][3] = fmaf(a0, wv.w, acc[0][3]);
        acc[1][0] = fmaf(a1, wv.x, acc[1][0]); acc[1][1] = fmaf(a1, wv.y, acc[1][1]);
        acc[1][2] = fmaf(a1, wv.z, acc[1][2]); acc[1][3] = fmaf(a1, wv.w, acc[1][3]);
        acc[2][0] = fmaf(a2, wv.x, acc[2][0]); acc[2][1] = fmaf(a2, wv.y, acc[2][1]);
        acc[2][2] = fmaf(a2, wv.z, acc[2][2]); acc[2][3] = fmaf(a2, wv.w, acc[2][3]);
        acc[3][0] = fmaf(a3, wv.x, acc[3][0]); acc[3][1] = fmaf(a3, wv.y, acc[3][1]);
        acc[3][2] = fmaf(a3, wv.z, acc[3][2]); acc[3][3] = fmaf(a3, wv.w, acc[3][3]);
    }

    #pragma unroll
    for (int i = 0; i < 4; ++i) {
        int gn = node0 + ty * 4 + i;
        if (gn < n) {
            float4 o = make_float4(acc[i][0], acc[i][1], acc[i][2], acc[i][3]);
            ((float4*)(hw + (long long)gn * FOUT))[tx] = o;
        }
    }
}

// ---------------- CSR aggregation (float4 lanes, 4x unroll) + BN stats ----------------
template <int FOUT>
__global__ __launch_bounds__(256) void k_agg(const float* __restrict__ hw,
                                             const ull* __restrict__ epack,
                                             const int* __restrict__ rp,
                                             const float* __restrict__ dis,
                                             const float* __restrict__ bias,
                                             float* __restrict__ y,
                                             float* __restrict__ stats, int n) {
    constexpr int LPN = FOUT / 4;          // lanes per node
    constexpr int NPB = 256 / LPN;         // nodes per block
    __shared__ float ssum[FOUT], ssq[FOUT];
    for (int i = threadIdx.x; i < FOUT; i += 256) { ssum[i] = 0.f; ssq[i] = 0.f; }
    __syncthreads();
    const int local = threadIdx.x / LPN;
    const int fq = threadIdx.x % LPN;      // float4 slot within row
    const float4* hw4 = (const float4*)hw;
    const float4 b4 = ((const float4*)bias)[fq];
    float4 lsum = make_float4(0.f, 0.f, 0.f, 0.f);
    float4 lsq  = make_float4(0.f, 0.f, 0.f, 0.f);

    for (long long base = (long long)blockIdx.x * NPB; base < n;
         base += (long long)gridDim.x * NPB) {
        int node = (int)base + local;
        if (node >= n) continue;
        int j0 = rp[node], j1 = rp[node + 1];
        float4 acc = make_float4(0.f, 0.f, 0.f, 0.f);
        int j = j0;
        for (; j + 4 <= j1; j += 4) {
            ull p0 = epack[j + 0], p1 = epack[j + 1];
            ull p2 = epack[j + 2], p3 = epack[j + 3];
            float4 r0 = hw4[(long long)(unsigned)p0 * LPN + fq];
            float4 r1 = hw4[(long long)(unsigned)p1 * LPN + fq];
            float4 r2 = hw4[(long long)(unsigned)p2 * LPN + fq];
            float4 r3 = hw4[(long long)(unsigned)p3 * LPN + fq];
            float w0 = __uint_as_float((unsigned)(p0 >> 32));
            float w1 = __uint_as_float((unsigned)(p1 >> 32));
            float w2 = __uint_as_float((unsigned)(p2 >> 32));
            float w3 = __uint_as_float((unsigned)(p3 >> 32));
            acc.x = fmaf(r0.x, w0, acc.x); acc.y = fmaf(r0.y, w0, acc.y);
            acc.z = fmaf(r0.z, w0, acc.z); acc.w = fmaf(r0.w, w0, acc.w);
            acc.x = fmaf(r1.x, w1, acc.x); acc.y = fmaf(r1.y, w1, acc.y);
            acc.z = fmaf(r1.z, w1, acc.z); acc.w = fmaf(r1.w, w1, acc.w);
            acc.x = fmaf(r2.x, w2, acc.x); acc.y = fmaf(r2.y, w2, acc.y);
            acc.z = fmaf(r2.z, w2, acc.z); acc.w = fmaf(r2.w, w2, acc.w);
            acc.x = fmaf(r3.x, w3, acc.x); acc.y = fmaf(r3.y, w3, acc.y);
            acc.z = fmaf(r3.z, w3, acc.z); acc.w = fmaf(r3.w, w3, acc.w);
        }
        for (; j < j1; ++j) {
            ull p = epack[j];
            float4 r = hw4[(long long)(unsigned)p * LPN + fq];
            float w = __uint_as_float((unsigned)(p >> 32));
            acc.x = fmaf(r.x, w, acc.x); acc.y = fmaf(r.y, w, acc.y);
            acc.z = fmaf(r.z, w, acc.z); acc.w = fmaf(r.w, w, acc.w);
        }
        float dv = dis[node];
        float sw = dv * dv;
        float4 hs = hw4[(long long)node * LPN + fq];
        float4 v;
        v.x = fmaf(sw, hs.x, acc.x) + b4.x;
        v.y = fmaf(sw, hs.y, acc.y) + b4.y;
        v.z = fmaf(sw, hs.z, acc.z) + b4.z;
        v.w = fmaf(sw, hs.w, acc.w) + b4.w;
        ((float4*)y)[(long long)node * LPN + fq] = v;
        lsum.x += v.x; lsum.y += v.y; lsum.z += v.z; lsum.w += v.w;
        lsq.x = fmaf(v.x, v.x, lsq.x); lsq.y = fmaf(v.y, v.y, lsq.y);
        lsq.z = fmaf(v.z, v.z, lsq.z); lsq.w = fmaf(v.w, v.w, lsq.w);
    }
    atomicAdd(&ssum[fq * 4 + 0], lsum.x); atomicAdd(&ssum[fq * 4 + 1], lsum.y);
    atomicAdd(&ssum[fq * 4 + 2], lsum.z); atomicAdd(&ssum[fq * 4 + 3], lsum.w);
    atomicAdd(&ssq[fq * 4 + 0], lsq.x);  atomicAdd(&ssq[fq * 4 + 1], lsq.y);
    atomicAdd(&ssq[fq * 4 + 2], lsq.z);  atomicAdd(&ssq[fq * 4 + 3], lsq.w);
    __syncthreads();
    for (int i = threadIdx.x; i < FOUT; i += 256) {
        atomicAdd(&stats[i], ssum[i]);
        atomicAdd(&stats[64 + i], ssq[i]);
    }
}

// ---------------- BN apply + LeakyReLU (in place) ----------------
__global__ void k_bn(float* __restrict__ y, const float* __restrict__ stats,
                     const float* __restrict__ gma, const float* __restrict__ bta,
                     int n, int fout_shift) {
    long long tid = (long long)blockIdx.x * blockDim.x + threadIdx.x;
    if (tid >= ((long long)n << fout_shift)) return;
    int f = (int)(tid & ((1 << fout_shift) - 1));
    float inv_n = 1.0f / (float)n;
    float m = stats[f] * inv_n;
    float var = fmaxf(stats[64 + f] * inv_n - m * m, 0.f);
    float sc = rsqrtf(var + 1e-5f) * gma[f];
    float sh = bta[f] - m * sc;
    float v = y[tid] * sc + sh;
    y[tid] = v > 0.f ? v : 0.1f * v;
}

// ---------------- pooling: one block per graph (batch sorted) ----------------
__global__ void k_pool_graph(const float* __restrict__ h, const int* __restrict__ batch,
                             int n, float* __restrict__ psum, float* __restrict__ pmax,
                             float* __restrict__ pcnt) {
    const int g = blockIdx.x;
    __shared__ int s_lo, s_hi;
    if (threadIdx.x == 0) {
        int lo = 0, hi = n;
        while (lo < hi) { int mid = (lo + hi) >> 1; if (batch[mid] < g) lo = mid + 1; else hi = mid; }
        s_lo = lo;
        hi = n;
        while (lo < hi) { int mid = (lo + hi) >> 1; if (batch[mid] < g + 1) lo = mid + 1; else hi = mid; }
        s_hi = lo;
    }
    __syncthreads();
    const int start = s_lo, end = s_hi;
    float lsum = 0.f, lmax = -3.0e38f;
    for (long long idx = (long long)start * 16 + threadIdx.x; idx < (long long)end * 16; idx += blockDim.x) {
        float v = h[idx];
        lsum += v;
        lmax = fmaxf(lmax, v);
    }
    __shared__ float ss[256], sm[256];
    ss[threadIdx.x] = lsum; sm[threadIdx.x] = lmax;
    __syncthreads();
    for (int off = 128; off >= 16; off >>= 1) {
        if (threadIdx.x < off) {
            ss[threadIdx.x] += ss[threadIdx.x + off];
            sm[threadIdx.x] = fmaxf(sm[threadIdx.x], sm[threadIdx.x + off]);
        }
        __syncthreads();
    }
    if (threadIdx.x < 16) {
        psum[g * 16 + threadIdx.x] = ss[threadIdx.x];
        pmax[g * 16 + threadIdx.x] = sm[threadIdx.x];
    }
    if (threadIdx.x == 0) pcnt[g] = (float)(end - start);
}

// ---------------- head: attention pooling + MLP + sigmoid ----------------
__global__ void k_head(const float* __restrict__ psum, const float* __restrict__ pmax,
                       const float* __restrict__ pcnt,
                       const float* __restrict__ attn_w, const float* __restrict__ attn_b,
                       const float* __restrict__ fc1_w, const float* __restrict__ fc1_b,
                       const float* __restrict__ fc2_w, const float* __restrict__ fc2_b,
                       const float* __restrict__ out_w, const float* __restrict__ out_b,
                       float* __restrict__ out) {
    int g = threadIdx.x;
    if (g >= GG) return;
    float xs[16], xm[16], xx[16];
    float c = fmaxf(pcnt[g], 1.0f);
    for (int f = 0; f < 16; ++f) {
        xs[f] = psum[(g << 4) + f];
        xm[f] = xs[f] / c;
        xx[f] = pmax[(g << 4) + f];
    }
    float lg[3];
    for (int cI = 0; cI < 3; ++cI) {
        float a = attn_b[cI];
        for (int f = 0; f < 16; ++f) {
            a += xm[f] * attn_w[f * 3 + cI];
            a += xx[f] * attn_w[(16 + f) * 3 + cI];
            a += xs[f] * attn_w[(32 + f) * 3 + cI];
        }
        lg[cI] = a;
    }
    float mx = fmaxf(lg[0], fmaxf(lg[1], lg[2]));
    float e0 = expf(lg[0] - mx), e1 = expf(lg[1] - mx), e2 = expf(lg[2] - mx);
    float inv = 1.0f / (e0 + e1 + e2);
    float a0 = e0 * inv, a1 = e1 * inv, a2 = e2 * inv;
    float xg[16];
    for (int f = 0; f < 16; ++f) xg[f] = a0 * xm[f] + a1 * xx[f] + a2 * xs[f];
    float t1[16];
    for (int j = 0; j < 16; ++j) {
        float a = fc1_b[j];
        for (int k = 0; k < 16; ++k) a += xg[k] * fc1_w[k * 16 + j];
        t1[j] = a > 0.f ? a : 0.1f * a;
    }
    float t2[8];
    for (int j = 0; j < 8; ++j) {
        float a = fc2_b[j];
        for (int k = 0; k < 16; ++k) a += t1[k] * fc2_w[k * 8 + j];
        t2[j] = a > 0.f ? a : 0.1f * a;
    }
    float o = out_b[0];
    for (int k = 0; k < 8; ++k) o += t2[k] * out_w[k];
    o = 1.0f / (1.0f + expf(-o));
    out[g] = o;
}

extern "C" void kernel_launch(void* const* d_in, const int* in_sizes, int n_in,
                              void* d_out, int out_size, void* d_ws, size_t ws_size,
                              hipStream_t stream) {
    const float* x      = (const float*)d_in[0];
    const float* W1     = (const float*)d_in[1];  const float* b1   = (const float*)d_in[2];
    const float* W2     = (const float*)d_in[3];  const float* b2   = (const float*)d_in[4];
    const float* W3     = (const float*)d_in[5];  const float* b3   = (const float*)d_in[6];
    const float* g1     = (const float*)d_in[7];  const float* be1  = (const float*)d_in[8];
    const float* g2     = (const float*)d_in[9];  const float* be2  = (const float*)d_in[10];
    const float* g3     = (const float*)d_in[11]; const float* be3  = (const float*)d_in[12];
    const float* attn_w = (const float*)d_in[13]; const float* attn_b = (const float*)d_in[14];
    const float* fc1_w  = (const float*)d_in[15]; const float* fc1_b  = (const float*)d_in[16];
    const float* fc2_w  = (const float*)d_in[17]; const float* fc2_b  = (const float*)d_in[18];
    const float* out_w  = (const float*)d_in[19]; const float* out_b  = (const float*)d_in[20];
    const int* edge_index = (const int*)d_in[21];
    const int* batch      = (const int*)d_in[22];

    const int N = in_sizes[0] / 128;
    const int E = in_sizes[21] / 2;
    const int* srcp = edge_index;
    const int* dstp = edge_index + E;
    const int nb = (N + 255) / 256;

    char* ws = (char*)d_ws;
    float* dis    = (float*)(ws);                 // N f32
    int*   cnt    = (int*)(ws + 0x80000);         // N int, reused as cursor
    int*   rp     = (int*)(ws + 0x100000);        // N+1 int
    int*   bsum   = (int*)(ws + 0x180000);        // <=512 int
    float* stats  = (float*)(ws + 0x182000);      // 128 f32
    float* psum   = stats + 128;
    float* pmax   = psum + GG * 16;
    float* pcnt   = pmax + GG * 16;
    ull*   epack  = (ull*)(ws + 0x190000);        // E * 8B
    float* buf1   = (float*)(ws + 0x190000 + (size_t)E * 8);  // N*64 f32 (y / h)
    float* buf2   = buf1 + (size_t)N * 64;        // N*64 f32 (hw)

    // ---- CSR build ----
    hipMemsetAsync(cnt, 0, (size_t)N * 4, stream);
    k_hist<<<(E + 255) / 256, 256, 0, stream>>>(dstp, cnt, E);
    k_dis<<<nb, 256, 0, stream>>>(cnt, dis, N);
    k_scanA<<<nb, 256, 0, stream>>>(cnt, rp, bsum, N);
    k_scanB<<<1, 512, 0, stream>>>(bsum, nb);
    k_scanC<<<nb, 256, 0, stream>>>(rp, bsum, cnt, N, E);
    k_scatter<<<(E + 255) / 256, 256, 0, stream>>>(srcp, dstp, dis, cnt, epack, E);

    // ---- layer 1 ----
    k_mm<128, 64><<<(N + 63) / 64, 256, 0, stream>>>(x, W1, buf2, N);
    hipMemsetAsync(stats, 0, 512, stream);
    k_agg<64><<<2048, 256, 0, stream>>>(buf2, epack, rp, dis, b1, buf1, stats, N);
    k_bn<<<(unsigned)(((long long)N * 64 + 255) / 256), 256, 0, stream>>>(
        buf1, stats, g1, be1, N, 6);

    // ---- layer 2 ----
    k_mm<64, 32><<<(N + 127) / 128, 256, 0, stream>>>(buf1, W2, buf2, N);
    hipMemsetAsync(stats, 0, 512, stream);
    k_agg<32><<<2048, 256, 0, stream>>>(buf2, epack, rp, dis, b2, buf1, stats, N);
    k_bn<<<(unsigned)(((long long)N * 32 + 255) / 256), 256, 0, stream>>>(
        buf1, stats, g2, be2, N, 5);

    // ---- layer 3 ----
    k_mm<32, 16><<<(N + 255) / 256, 256, 0, stream>>>(buf1, W3, buf2, N);
    hipMemsetAsync(stats, 0, 512, stream);
    k_agg<16><<<2048, 256, 0, stream>>>(buf2, epack, rp, dis, b3, buf1, stats, N);
    k_bn<<<(unsigned)(((long long)N * 16 + 255) / 256), 256, 0, stream>>>(
        buf1, stats, g3, be3, N, 4);

    // ---- pooling + head ----
    k_pool_graph<<<GG, 256, 0, stream>>>(buf1, batch, N, psum, pmax, pcnt);
    k_head<<<1, 64, 0, stream>>>(psum, pmax, pcnt, attn_w, attn_b,
                                 fc1_w, fc1_b, fc2_w, fc2_b, out_w, out_b,
                                 (float*)d_out);
}

// Round 8
// 627.451 us; speedup vs baseline: 3.4105x; 1.0228x over previous
//
#include <hip/hip_runtime.h>

#define GG 64   // num_graphs (fixed by problem)
typedef unsigned long long ull;
typedef unsigned short u16;

__device__ __forceinline__ u16 f2b(float x) {          // fp32 -> bf16 (RN-even)
    unsigned u = __float_as_uint(x);
    return (u16)((u + 0x7FFFu + ((u >> 16) & 1u)) >> 16);
}

// unpack uint4 (8 bf16) and fma into acc[8]
__device__ __forceinline__ void fma8(const uint4 q, float w, float* acc) {
    acc[0] = fmaf(__uint_as_float(q.x << 16), w, acc[0]);
    acc[1] = fmaf(__uint_as_float(q.x & 0xFFFF0000u), w, acc[1]);
    acc[2] = fmaf(__uint_as_float(q.y << 16), w, acc[2]);
    acc[3] = fmaf(__uint_as_float(q.y & 0xFFFF0000u), w, acc[3]);
    acc[4] = fmaf(__uint_as_float(q.z << 16), w, acc[4]);
    acc[5] = fmaf(__uint_as_float(q.z & 0xFFFF0000u), w, acc[5]);
    acc[6] = fmaf(__uint_as_float(q.w << 16), w, acc[6]);
    acc[7] = fmaf(__uint_as_float(q.w & 0xFFFF0000u), w, acc[7]);
}

// ---------------- CSR build ----------------
__global__ void k_hist(const int* __restrict__ dst, int* __restrict__ cnt, int E) {
    int e = blockIdx.x * blockDim.x + threadIdx.x;
    if (e < E) atomicAdd(&cnt[dst[e]], 1);
}

__global__ void k_dis(const int* __restrict__ cnt, float* __restrict__ dis, int n) {
    int i = blockIdx.x * blockDim.x + threadIdx.x;
    if (i < n) dis[i] = rsqrtf((float)cnt[i] + 1.0f);
}

__global__ void k_scanA(const int* __restrict__ cnt, int* __restrict__ rp,
                        int* __restrict__ bsum, int n) {
    __shared__ int s[256];
    int i = blockIdx.x * 256 + threadIdx.x;
    int v = (i < n) ? cnt[i] : 0;
    s[threadIdx.x] = v;
    __syncthreads();
    for (int off = 1; off < 256; off <<= 1) {
        int t = (threadIdx.x >= off) ? s[threadIdx.x - off] : 0;
        __syncthreads();
        s[threadIdx.x] += t;
        __syncthreads();
    }
    if (i < n) rp[i] = s[threadIdx.x] - v;
    if (threadIdx.x == 255) bsum[blockIdx.x] = s[255];
}

__global__ void k_scanB(int* __restrict__ bsum, int nb) {
    __shared__ int s[512];
    int v = (threadIdx.x < nb) ? bsum[threadIdx.x] : 0;
    s[threadIdx.x] = v;
    __syncthreads();
    for (int off = 1; off < 512; off <<= 1) {
        int t = (threadIdx.x >= off) ? s[threadIdx.x - off] : 0;
        __syncthreads();
        s[threadIdx.x] += t;
        __syncthreads();
    }
    if (threadIdx.x < nb) bsum[threadIdx.x] = s[threadIdx.x] - v;
}

__global__ void k_scanC(int* __restrict__ rp, const int* __restrict__ bsum,
                        int* __restrict__ cursor, int n, int E) {
    int i = blockIdx.x * 256 + threadIdx.x;
    if (i < n) {
        int r = rp[i] + bsum[blockIdx.x];
        rp[i] = r;
        cursor[i] = r;
    }
    if (i == 0) rp[n] = E;
}

__global__ void k_scatter(const int* __restrict__ src, const int* __restrict__ dst,
                          const float* __restrict__ dis, int* __restrict__ cursor,
                          ull* __restrict__ epack, int E) {
    int e = blockIdx.x * blockDim.x + threadIdx.x;
    if (e >= E) return;
    int s = src[e], d = dst[e];
    float w = dis[s] * dis[d];
    int pos = atomicAdd(&cursor[d], 1);
    epack[pos] = ((ull)__float_as_uint(w) << 32) | (unsigned)s;
}

// ---------------- tiled GEMM: hwb[n,FOUT](bf16) = h[n,FIN] @ W[FIN,FOUT] ----------
template <int FIN, int FOUT>
__global__ __launch_bounds__(256) void k_mm(const float* __restrict__ h,
                                            const float* __restrict__ W,
                                            u16* __restrict__ hw, int n) {
    constexpr int FX  = FOUT / 4;
    constexpr int TY  = 256 / FX;
    constexpr int NT  = TY * 4;
    constexpr int LDA = FIN + ((FOUT == 64) ? 2 : 1);
    __shared__ float sA[NT * LDA];
    __shared__ float sW[FIN * FOUT];

    for (int i = threadIdx.x; i < FIN * FOUT / 4; i += 256)
        ((float4*)sW)[i] = ((const float4*)W)[i];

    const int node0 = blockIdx.x * NT;
    constexpr int LD4 = NT * FIN / 4 / 256;
    #pragma unroll
    for (int i = 0; i < LD4; ++i) {
        int idx4 = i * 256 + threadIdx.x;
        int row = idx4 / (FIN / 4);
        int c4  = idx4 % (FIN / 4);
        int gn  = node0 + row;
        float4 v = make_float4(0.f, 0.f, 0.f, 0.f);
        if (gn < n) v = ((const float4*)(h + (long long)gn * FIN))[c4];
        float* p = &sA[row * LDA + c4 * 4];
        p[0] = v.x; p[1] = v.y; p[2] = v.z; p[3] = v.w;
    }
    __syncthreads();

    const int tx = threadIdx.x % FX;
    const int ty = threadIdx.x / FX;
    float acc[4][4];
    #pragma unroll
    for (int i = 0; i < 4; ++i)
        #pragma unroll
        for (int j = 0; j < 4; ++j) acc[i][j] = 0.f;

    #pragma unroll 8
    for (int k = 0; k < FIN; ++k) {
        float4 wv = *((const float4*)&sW[k * FOUT + tx * 4]);
        float a0 = sA[(ty * 4 + 0) * LDA + k];
        float a1 = sA[(ty * 4 + 1) * LDA + k];
        float a2 = sA[(ty * 4 + 2) * LDA + k];
        float a3 = sA[(ty * 4 + 3) * LDA + k];
        acc[0][0] = fmaf(a0, wv.x, acc[0][0]); acc[0][1] = fmaf(a0, wv.y, acc[0][1]);
        acc[0][2] = fmaf(a0, wv.z, acc[0][2]); acc[0][3] = fmaf(a0, wv.w, acc[0][3]);
        acc[1][0] = fmaf(a1, wv.x, acc[1][0]); acc[1][1] = fmaf(a1, wv.y, acc[1][1]);
        acc[1][2] = fmaf(a1, wv.z, acc[1][2]); acc[1][3] = fmaf(a1, wv.w, acc[1][3]);
        acc[2][0] = fmaf(a2, wv.x, acc[2][0]); acc[2][1] = fmaf(a2, wv.y, acc[2][1]);
        acc[2][2] = fmaf(a2, wv.z, acc[2][2]); acc[2][3] = fmaf(a2, wv.w, acc[2][3]);
        acc[3][0] = fmaf(a3, wv.x, acc[3][0]); acc[3][1] = fmaf(a3, wv.y, acc[3][1]);
        acc[3][2] = fmaf(a3, wv.z, acc[3][2]); acc[3][3] = fmaf(a3, wv.w, acc[3][3]);
    }

    #pragma unroll
    for (int i = 0; i < 4; ++i) {
        int gn = node0 + ty * 4 + i;
        if (gn < n) {
            ushort4 o;
            o.x = f2b(acc[i][0]); o.y = f2b(acc[i][1]);
            o.z = f2b(acc[i][2]); o.w = f2b(acc[i][3]);
            ((ushort4*)(hw + (long long)gn * FOUT))[tx] = o;
        }
    }
}

// ---------------- CSR aggregation (bf16 gather, 8 feats/lane) + BN stats ----------
template <int FOUT>
__global__ __launch_bounds__(256) void k_agg(const u16* __restrict__ hwb,
                                             const ull* __restrict__ epack,
                                             const int* __restrict__ rp,
                                             const float* __restrict__ dis,
                                             const float* __restrict__ bias,
                                             float* __restrict__ y,
                                             float* __restrict__ stats, int n) {
    constexpr int LPN = FOUT / 8;          // lanes per node (uint4 = 8 bf16)
    constexpr int NPB = 256 / LPN;         // nodes per block
    constexpr int RS  = FOUT / 8;          // row stride in uint4
    __shared__ float ssum[FOUT], ssq[FOUT];
    for (int i = threadIdx.x; i < FOUT; i += 256) { ssum[i] = 0.f; ssq[i] = 0.f; }
    __syncthreads();
    const int local = threadIdx.x / LPN;
    const int fq = threadIdx.x % LPN;
    const uint4* hw4 = (const uint4*)hwb;
    float b8[8];
    #pragma unroll
    for (int i = 0; i < 8; ++i) b8[i] = bias[fq * 8 + i];
    float lsum[8] = {0,0,0,0,0,0,0,0}, lsq[8] = {0,0,0,0,0,0,0,0};

    for (long long base = (long long)blockIdx.x * NPB; base < n;
         base += (long long)gridDim.x * NPB) {
        int node = (int)base + local;
        if (node >= n) continue;
        int j0 = rp[node], j1 = rp[node + 1];
        float acc[8] = {0,0,0,0,0,0,0,0};
        int j = j0;
        for (; j + 4 <= j1; j += 4) {
            ull p0 = epack[j + 0], p1 = epack[j + 1];
            ull p2 = epack[j + 2], p3 = epack[j + 3];
            uint4 q0 = hw4[(long long)(unsigned)p0 * RS + fq];
            uint4 q1 = hw4[(long long)(unsigned)p1 * RS + fq];
            uint4 q2 = hw4[(long long)(unsigned)p2 * RS + fq];
            uint4 q3 = hw4[(long long)(unsigned)p3 * RS + fq];
            fma8(q0, __uint_as_float((unsigned)(p0 >> 32)), acc);
            fma8(q1, __uint_as_float((unsigned)(p1 >> 32)), acc);
            fma8(q2, __uint_as_float((unsigned)(p2 >> 32)), acc);
            fma8(q3, __uint_as_float((unsigned)(p3 >> 32)), acc);
        }
        for (; j < j1; ++j) {
            ull p = epack[j];
            uint4 q = hw4[(long long)(unsigned)p * RS + fq];
            fma8(q, __uint_as_float((unsigned)(p >> 32)), acc);
        }
        float dv = dis[node];
        float sw = dv * dv;
        uint4 qs = hw4[(long long)node * RS + fq];
        fma8(qs, sw, acc);
        #pragma unroll
        for (int i = 0; i < 8; ++i) acc[i] += b8[i];
        float4* y4 = (float4*)y;
        long long o = (long long)node * (FOUT / 4) + fq * 2;
        y4[o]     = make_float4(acc[0], acc[1], acc[2], acc[3]);
        y4[o + 1] = make_float4(acc[4], acc[5], acc[6], acc[7]);
        #pragma unroll
        for (int i = 0; i < 8; ++i) {
            lsum[i] += acc[i];
            lsq[i] = fmaf(acc[i], acc[i], lsq[i]);
        }
    }
    #pragma unroll
    for (int i = 0; i < 8; ++i) {
        atomicAdd(&ssum[fq * 8 + i], lsum[i]);
        atomicAdd(&ssq[fq * 8 + i], lsq[i]);
    }
    __syncthreads();
    for (int i = threadIdx.x; i < FOUT; i += 256) {
        atomicAdd(&stats[i], ssum[i]);
        atomicAdd(&stats[64 + i], ssq[i]);
    }
}

// ---------------- BN apply + LeakyReLU (in place) ----------------
__global__ void k_bn(float* __restrict__ y, const float* __restrict__ stats,
                     const float* __restrict__ gma, const float* __restrict__ bta,
                     int n, int fout_shift) {
    long long tid = (long long)blockIdx.x * blockDim.x + threadIdx.x;
    if (tid >= ((long long)n << fout_shift)) return;
    int f = (int)(tid & ((1 << fout_shift) - 1));
    float inv_n = 1.0f / (float)n;
    float m = stats[f] * inv_n;
    float var = fmaxf(stats[64 + f] * inv_n - m * m, 0.f);
    float sc = rsqrtf(var + 1e-5f) * gma[f];
    float sh = bta[f] - m * sc;
    float v = y[tid] * sc + sh;
    y[tid] = v > 0.f ? v : 0.1f * v;
}

// ---------------- pooling: one block per graph (batch sorted) ----------------
__global__ void k_pool_graph(const float* __restrict__ h, const int* __restrict__ batch,
                             int n, float* __restrict__ psum, float* __restrict__ pmax,
                             float* __restrict__ pcnt) {
    const int g = blockIdx.x;
    __shared__ int s_lo, s_hi;
    if (threadIdx.x == 0) {
        int lo = 0, hi = n;
        while (lo < hi) { int mid = (lo + hi) >> 1; if (batch[mid] < g) lo = mid + 1; else hi = mid; }
        s_lo = lo;
        hi = n;
        while (lo < hi) { int mid = (lo + hi) >> 1; if (batch[mid] < g + 1) lo = mid + 1; else hi = mid; }
        s_hi = lo;
    }
    __syncthreads();
    const int start = s_lo, end = s_hi;
    float lsum = 0.f, lmax = -3.0e38f;
    for (long long idx = (long long)start * 16 + threadIdx.x; idx < (long long)end * 16; idx += blockDim.x) {
        float v = h[idx];
        lsum += v;
        lmax = fmaxf(lmax, v);
    }
    __shared__ float ss[256], sm[256];
    ss[threadIdx.x] = lsum; sm[threadIdx.x] = lmax;
    __syncthreads();
    for (int off = 128; off >= 16; off >>= 1) {
        if (threadIdx.x < off) {
            ss[threadIdx.x] += ss[threadIdx.x + off];
            sm[threadIdx.x] = fmaxf(sm[threadIdx.x], sm[threadIdx.x + off]);
        }
        __syncthreads();
    }
    if (threadIdx.x < 16) {
        psum[g * 16 + threadIdx.x] = ss[threadIdx.x];
        pmax[g * 16 + threadIdx.x] = sm[threadIdx.x];
    }
    if (threadIdx.x == 0) pcnt[g] = (float)(end - start);
}

// ---------------- head ----------------
__global__ void k_head(const float* __restrict__ psum, const float* __restrict__ pmax,
                       const float* __restrict__ pcnt,
                       const float* __restrict__ attn_w, const float* __restrict__ attn_b,
                       const float* __restrict__ fc1_w, const float* __restrict__ fc1_b,
                       const float* __restrict__ fc2_w, const float* __restrict__ fc2_b,
                       const float* __restrict__ out_w, const float* __restrict__ out_b,
                       float* __restrict__ out) {
    int g = threadIdx.x;
    if (g >= GG) return;
    float xs[16], xm[16], xx[16];
    float c = fmaxf(pcnt[g], 1.0f);
    for (int f = 0; f < 16; ++f) {
        xs[f] = psum[(g << 4) + f];
        xm[f] = xs[f] / c;
        xx[f] = pmax[(g << 4) + f];
    }
    float lg[3];
    for (int cI = 0; cI < 3; ++cI) {
        float a = attn_b[cI];
        for (int f = 0; f < 16; ++f) {
            a += xm[f] * attn_w[f * 3 + cI];
            a += xx[f] * attn_w[(16 + f) * 3 + cI];
            a += xs[f] * attn_w[(32 + f) * 3 + cI];
        }
        lg[cI] = a;
    }
    float mx = fmaxf(lg[0], fmaxf(lg[1], lg[2]));
    float e0 = expf(lg[0] - mx), e1 = expf(lg[1] - mx), e2 = expf(lg[2] - mx);
    float inv = 1.0f / (e0 + e1 + e2);
    float a0 = e0 * inv, a1 = e1 * inv, a2 = e2 * inv;
    float xg[16];
    for (int f = 0; f < 16; ++f) xg[f] = a0 * xm[f] + a1 * xx[f] + a2 * xs[f];
    float t1[16];
    for (int j = 0; j < 16; ++j) {
        float a = fc1_b[j];
        for (int k = 0; k < 16; ++k) a += xg[k] * fc1_w[k * 16 + j];
        t1[j] = a > 0.f ? a : 0.1f * a;
    }
    float t2[8];
    for (int j = 0; j < 8; ++j) {
        float a = fc2_b[j];
        for (int k = 0; k < 16; ++k) a += t1[k] * fc2_w[k * 8 + j];
        t2[j] = a > 0.f ? a : 0.1f * a;
    }
    float o = out_b[0];
    for (int k = 0; k < 8; ++k) o += t2[k] * out_w[k];
    o = 1.0f / (1.0f + expf(-o));
    out[g] = o;
}

extern "C" void kernel_launch(void* const* d_in, const int* in_sizes, int n_in,
                              void* d_out, int out_size, void* d_ws, size_t ws_size,
                              hipStream_t stream) {
    const float* x      = (const float*)d_in[0];
    const float* W1     = (const float*)d_in[1];  const float* b1   = (const float*)d_in[2];
    const float* W2     = (const float*)d_in[3];  const float* b2   = (const float*)d_in[4];
    const float* W3     = (const float*)d_in[5];  const float* b3   = (const float*)d_in[6];
    const float* g1     = (const float*)d_in[7];  const float* be1  = (const float*)d_in[8];
    const float* g2     = (const float*)d_in[9];  const float* be2  = (const float*)d_in[10];
    const float* g3     = (const float*)d_in[11]; const float* be3  = (const float*)d_in[12];
    const float* attn_w = (const float*)d_in[13]; const float* attn_b = (const float*)d_in[14];
    const float* fc1_w  = (const float*)d_in[15]; const float* fc1_b  = (const float*)d_in[16];
    const float* fc2_w  = (const float*)d_in[17]; const float* fc2_b  = (const float*)d_in[18];
    const float* out_w  = (const float*)d_in[19]; const float* out_b  = (const float*)d_in[20];
    const int* edge_index = (const int*)d_in[21];
    const int* batch      = (const int*)d_in[22];

    const int N = in_sizes[0] / 128;
    const int E = in_sizes[21] / 2;
    const int* srcp = edge_index;
    const int* dstp = edge_index + E;
    const int nb = (N + 255) / 256;

    char* ws = (char*)d_ws;
    float* dis    = (float*)(ws);                 // N f32
    int*   cnt    = (int*)(ws + 0x80000);         // N int (reused as cursor)
    int*   rp     = (int*)(ws + 0x100000);        // N+1 int
    int*   bsum   = (int*)(ws + 0x180000);        // <=512 int
    float* stats  = (float*)(ws + 0x182000);      // 128 f32
    float* psum   = stats + 128;
    float* pmax   = psum + GG * 16;
    float* pcnt   = pmax + GG * 16;
    ull*   epack  = (ull*)(ws + 0x190000);        // E * 8B
    float* buf1   = (float*)(ws + 0x190000 + (size_t)E * 8);  // N*64 f32 (y / h)
    u16*   hwb    = (u16*)(buf1 + (size_t)N * 64);            // N*64 bf16 (hw)

    // ---- CSR build ----
    hipMemsetAsync(cnt, 0, (size_t)N * 4, stream);
    k_hist<<<(E + 255) / 256, 256, 0, stream>>>(dstp, cnt, E);
    k_dis<<<nb, 256, 0, stream>>>(cnt, dis, N);
    k_scanA<<<nb, 256, 0, stream>>>(cnt, rp, bsum, N);
    k_scanB<<<1, 512, 0, stream>>>(bsum, nb);
    k_scanC<<<nb, 256, 0, stream>>>(rp, bsum, cnt, N, E);
    k_scatter<<<(E + 255) / 256, 256, 0, stream>>>(srcp, dstp, dis, cnt, epack, E);

    // ---- layer 1 ----
    k_mm<128, 64><<<(N + 63) / 64, 256, 0, stream>>>(x, W1, hwb, N);
    hipMemsetAsync(stats, 0, 512, stream);
    k_agg<64><<<2048, 256, 0, stream>>>(hwb, epack, rp, dis, b1, buf1, stats, N);
    k_bn<<<(unsigned)(((long long)N * 64 + 255) / 256), 256, 0, stream>>>(
        buf1, stats, g1, be1, N, 6);

    // ---- layer 2 ----
    k_mm<64, 32><<<(N + 127) / 128, 256, 0, stream>>>(buf1, W2, hwb, N);
    hipMemsetAsync(stats, 0, 512, stream);
    k_agg<32><<<2048, 256, 0, stream>>>(hwb, epack, rp, dis, b2, buf1, stats, N);
    k_bn<<<(unsigned)(((long long)N * 32 + 255) / 256), 256, 0, stream>>>(
        buf1, stats, g2, be2, N, 5);

    // ---- layer 3 ----
    k_mm<32, 16><<<(N + 255) / 256, 256, 0, stream>>>(buf1, W3, hwb, N);
    hipMemsetAsync(stats, 0, 512, stream);
    k_agg<16><<<2048, 256, 0, stream>>>(hwb, epack, rp, dis, b3, buf1, stats, N);
    k_bn<<<(unsigned)(((long long)N * 16 + 255) / 256), 256, 0, stream>>>(
        buf1, stats, g3, be3, N, 4);

    // ---- pooling + head ----
    k_pool_graph<<<GG, 256, 0, stream>>>(buf1, batch, N, psum, pmax, pcnt);
    k_head<<<1, 64, 0, stream>>>(psum, pmax, pcnt, attn_w, attn_b,
                                 fc1_w, fc1_b, fc2_w, fc2_b, out_w, out_b,
                                 (float*)d_out);
}